// Round 3
// baseline (997.223 us; speedup 1.0000x reference)
//
#include <hip/hip_runtime.h>
#include <hip/hip_cooperative_groups.h>
#include <math.h>

namespace cg = cooperative_groups;

#define NUSER 2560
#define NITEM 3584
#define NN    6144
#define EDIM  64
#define NNZ   200000
#define DQK   256
#define KTOP  5
#define SPLITS 16
#define TPS    3          // 48 cand tiles / 16 splits
#define TPB   256

// ================================================================ cooperative GNN pipeline
// phases: zero hist | hist | scan | scatter | spmm1 | spmm2 | qm+mean
struct CoopParams {
    const float* user; const float* item;
    const int* nrows; const int* ncols; const float* nvals;
    const int* arows; const int* acols; const float* avals;
    int* cnt_n; int* cnt_a; int* start_n; int* start_a; int* cur_n; int* cur_a;
    int2* cv_n; int2* cv_a;
    float* ego1; float* ego2; float* Qm; float* outmean;
};

__global__ __launch_bounds__(TPB, 2) void gnn_coop_kernel(CoopParams p) {
    cg::grid_group grid = cg::this_grid();
    const int t = threadIdx.x;
    const int gtid = blockIdx.x * TPB + t;
    const int GSZ = gridDim.x * TPB;          // 131072
    __shared__ int sc[TPB];

    // phase0: zero histograms
    for (int i = gtid; i < NN; i += GSZ) { p.cnt_n[i] = 0; p.cnt_a[i] = 0; }
    grid.sync();

    // phase1: histogram
    for (int i = gtid; i < 2 * NNZ; i += GSZ) {
        if (i < NNZ) atomicAdd(&p.cnt_n[p.nrows[i]], 1);
        else         atomicAdd(&p.cnt_a[p.arows[i - NNZ]], 1);
    }
    grid.sync();

    // phase2: exclusive scan (block 0 -> norm, block 1 -> adj)
    if (blockIdx.x < 2) {
        const int* cnt = blockIdx.x ? p.cnt_a : p.cnt_n;
        int* start = blockIdx.x ? p.start_a : p.start_n;
        int* cur   = blockIdx.x ? p.cur_a   : p.cur_n;
        int base = t * 24, s = 0;
        for (int j = 0; j < 24; ++j) s += cnt[base + j];
        sc[t] = s; __syncthreads();
        for (int off = 1; off < TPB; off <<= 1) {
            int v = (t >= off) ? sc[t - off] : 0;
            __syncthreads(); sc[t] += v; __syncthreads();
        }
        int ex = sc[t] - s;
        for (int j = 0; j < 24; ++j) {
            int c = cnt[base + j];
            start[base + j] = ex; cur[base + j] = ex; ex += c;
        }
        if (t == TPB - 1) start[NN] = ex;
    }
    grid.sync();

    // phase3: scatter into CSR
    for (int i = gtid; i < 2 * NNZ; i += GSZ) {
        if (i < NNZ) {
            int pos = atomicAdd(&p.cur_n[p.nrows[i]], 1);
            p.cv_n[pos] = make_int2(p.ncols[i], __float_as_int(p.nvals[i]));
        } else {
            int h = i - NNZ;
            int pos = atomicAdd(&p.cur_a[p.arows[h]], 1);
            p.cv_a[pos] = make_int2(p.acols[h], __float_as_int(p.avals[h]));
        }
    }
    __threadfence();
    grid.sync();

    const int w = blockIdx.x * 4 + (t >> 6), lane = t & 63;
    const int NW = gridDim.x * 4;             // 2048 waves

    // phase4: ego1 = A_norm @ ego0
    for (int r = w; r < NN; r += NW) {
        int s0 = p.start_n[r], e0 = p.start_n[r + 1];
        float acc = 0.f;
        for (int j = s0; j < e0; ++j) {
            int2 c = p.cv_n[j];
            float x = (c.x < NUSER) ? p.user[c.x * EDIM + lane]
                                    : p.item[(c.x - NUSER) * EDIM + lane];
            acc = fmaf(__int_as_float(c.y), x, acc);
        }
        p.ego1[r * EDIM + lane] = acc;
    }
    __threadfence();
    grid.sync();

    // phase5: ego2 = A_norm @ ego1
    for (int r = w; r < NN; r += NW) {
        int s0 = p.start_n[r], e0 = p.start_n[r + 1];
        float acc = 0.f;
        for (int j = s0; j < e0; ++j) {
            int2 c = p.cv_n[j];
            acc = fmaf(__int_as_float(c.y), p.ego1[c.x * EDIM + lane], acc);
        }
        p.ego2[r * EDIM + lane] = acc;
    }
    __threadfence();
    grid.sync();

    // phase6: Qm = ego2 + 0.5*(A@ego2); outmean = 0.5*(ego0+ego1)
    for (int r = w; r < NN; r += NW) {
        int s0 = p.start_a[r], e0 = p.start_a[r + 1];
        float acc = 0.f;
        for (int j = s0; j < e0; ++j) {
            int2 c = p.cv_a[j];
            acc = fmaf(__int_as_float(c.y), p.ego2[c.x * EDIM + lane], acc);
        }
        int o = r * EDIM + lane;
        p.Qm[o] = p.ego2[o] + 0.5f * acc;
        float e0v = (r < NUSER) ? p.user[o] : p.item[o - NUSER * EDIM];
        p.outmean[o] = 0.5f * (e0v + p.ego1[o]);
    }
}

// ================================================================ QKV GEMM (validated in R1/R2)
__global__ __launch_bounds__(TPB, 3) void qkv_gemm_kernel(
        const float* __restrict__ A,
        const float* __restrict__ Wq, const float* __restrict__ bq,
        const float* __restrict__ Wk, const float* __restrict__ bk,
        const float* __restrict__ Wv, const float* __restrict__ bv,
        float* __restrict__ Qa, float* __restrict__ Ka, float* __restrict__ Va) {
    const float* W; const float* b; float* out;
    if (blockIdx.z == 0)      { W = Wq; b = bq; out = Qa; }
    else if (blockIdx.z == 1) { W = Wk; b = bk; out = Ka; }
    else                      { W = Wv; b = bv; out = Va; }

    __shared__ __align__(16) float smem[64 * 64 + 128 * 64];
    float* As = smem;
    float* Bs = smem + 4096;
    int t = threadIdx.x, tx = t & 15, ty = t >> 4;
    int r0 = blockIdx.x * 64, d0 = blockIdx.y * 128;

    {
        int r = t & 63, eb = (t >> 6) * 16;
#pragma unroll
        for (int rep = 0; rep < 4; ++rep) {
            int e0 = eb + rep * 4;
            float4 v = *(const float4*)&A[(r0 + r) * EDIM + e0];
            As[(e0 + 0) * 64 + r] = v.x; As[(e0 + 1) * 64 + r] = v.y;
            As[(e0 + 2) * 64 + r] = v.z; As[(e0 + 3) * 64 + r] = v.w;
        }
    }
    {
        int d = t & 127, eb = (t >> 7) * 32;
#pragma unroll
        for (int rep = 0; rep < 8; ++rep) {
            int e0 = eb + rep * 4;
            float4 v = *(const float4*)&W[(d0 + d) * EDIM + e0];
            Bs[(e0 + 0) * 128 + d] = v.x; Bs[(e0 + 1) * 128 + d] = v.y;
            Bs[(e0 + 2) * 128 + d] = v.z; Bs[(e0 + 3) * 128 + d] = v.w;
        }
    }
    __syncthreads();

    float acc[4][8];
#pragma unroll
    for (int i = 0; i < 4; ++i)
#pragma unroll
        for (int j = 0; j < 8; ++j) acc[i][j] = 0.f;

#pragma unroll 4
    for (int e = 0; e < 64; ++e) {
        float4 a  = *(const float4*)&As[e * 64 + ty * 4];
        float4 b0 = *(const float4*)&Bs[e * 128 + tx * 4];
        float4 b1 = *(const float4*)&Bs[e * 128 + 64 + tx * 4];
        float ar[4] = {a.x, a.y, a.z, a.w};
#pragma unroll
        for (int i = 0; i < 4; ++i) {
            acc[i][0] = fmaf(ar[i], b0.x, acc[i][0]);
            acc[i][1] = fmaf(ar[i], b0.y, acc[i][1]);
            acc[i][2] = fmaf(ar[i], b0.z, acc[i][2]);
            acc[i][3] = fmaf(ar[i], b0.w, acc[i][3]);
            acc[i][4] = fmaf(ar[i], b1.x, acc[i][4]);
            acc[i][5] = fmaf(ar[i], b1.y, acc[i][5]);
            acc[i][6] = fmaf(ar[i], b1.z, acc[i][6]);
            acc[i][7] = fmaf(ar[i], b1.w, acc[i][7]);
        }
    }
    float4 bias0 = *(const float4*)&b[d0 + tx * 4];
    float4 bias1 = *(const float4*)&b[d0 + 64 + tx * 4];
#pragma unroll
    for (int i = 0; i < 4; ++i) {
        int r = r0 + ty * 4 + i;
        float4 o0 = make_float4(acc[i][0] + bias0.x, acc[i][1] + bias0.y,
                                acc[i][2] + bias0.z, acc[i][3] + bias0.w);
        float4 o1 = make_float4(acc[i][4] + bias1.x, acc[i][5] + bias1.y,
                                acc[i][6] + bias1.z, acc[i][7] + bias1.w);
        *(float4*)&out[r * DQK + d0 + tx * 4] = o0;
        *(float4*)&out[r * DQK + d0 + 64 + tx * 4] = o1;
    }
}

// ================================================================ fused sim top-5 (8x8 microtile, both LDS)
__device__ __forceinline__ void ins5(float v, int ci, float tv[KTOP], int ti[KTOP]) {
    if (v > tv[4]) {
#pragma unroll
        for (int k = 4; k >= 1; --k) {
            bool sh = v > tv[k];
            bool ph = v > tv[k - 1];
            float nv = ph ? tv[k - 1] : v;
            int   ni = ph ? ti[k - 1] : ci;
            if (sh) { tv[k] = nv; ti[k] = ni; }
        }
        if (v > tv[0]) { tv[0] = v; ti[0] = ci; }
    }
}

__global__ __launch_bounds__(TPB, 2) void topk_partial_kernel(
        const float* __restrict__ Qm, const float* __restrict__ P,
        float* __restrict__ pval, int* __restrict__ pidx) {
    __shared__ __align__(16) float smem[16384];   // 64 KB: Qs[64][128] + Ps[64][128]
    float* Qs = smem;
    float* Ps = smem + 8192;
    int t = threadIdx.x, tx = t & 15, ty = t >> 4;
    int r0 = blockIdx.x * 128;
    int s  = blockIdx.y;

    { // stage Q transposed (once per block)
        int r = t & 127, q = t >> 7;
#pragma unroll
        for (int rep = 0; rep < 8; ++rep) {
            int e = q * 32 + rep * 4;
            float4 v = *(const float4*)&Qm[(r0 + r) * EDIM + e];
            Qs[(e + 0) * 128 + r] = v.x;
            Qs[(e + 1) * 128 + r] = v.y;
            Qs[(e + 2) * 128 + r] = v.z;
            Qs[(e + 3) * 128 + r] = v.w;
        }
    }

    float t5v[8][KTOP]; int t5i[8][KTOP];
#pragma unroll
    for (int i = 0; i < 8; ++i)
#pragma unroll
        for (int k = 0; k < KTOP; ++k) { t5v[i][k] = -INFINITY; t5i[i][k] = 0x7fffffff; }

    for (int tile = 0; tile < TPS; ++tile) {
        int c0 = (s * TPS + tile) * 128;
        __syncthreads();
        { // stage P tile transposed
            int c = t & 127, q = t >> 7;
#pragma unroll
            for (int rep = 0; rep < 8; ++rep) {
                int e = q * 32 + rep * 4;
                float4 v = *(const float4*)&P[(c0 + c) * EDIM + e];
                Ps[(e + 0) * 128 + c] = v.x;
                Ps[(e + 1) * 128 + c] = v.y;
                Ps[(e + 2) * 128 + c] = v.z;
                Ps[(e + 3) * 128 + c] = v.w;
            }
        }
        __syncthreads();

        float acc[8][8];
#pragma unroll
        for (int i = 0; i < 8; ++i)
#pragma unroll
            for (int j = 0; j < 8; ++j) acc[i][j] = 0.f;

#pragma unroll 2
        for (int e = 0; e < 64; ++e) {
            float4 a0 = *(const float4*)&Qs[e * 128 + ty * 4];
            float4 a1 = *(const float4*)&Qs[e * 128 + 64 + ty * 4];
            float4 b0 = *(const float4*)&Ps[e * 128 + tx * 4];
            float4 b1 = *(const float4*)&Ps[e * 128 + 64 + tx * 4];
            float ar[8] = {a0.x, a0.y, a0.z, a0.w, a1.x, a1.y, a1.z, a1.w};
            float br[8] = {b0.x, b0.y, b0.z, b0.w, b1.x, b1.y, b1.z, b1.w};
#pragma unroll
            for (int i = 0; i < 8; ++i)
#pragma unroll
                for (int j = 0; j < 8; ++j)
                    acc[i][j] = fmaf(ar[i], br[j], acc[i][j]);
        }

        // candidate index increasing in j keeps lowest-index-on-tie semantics
#pragma unroll
        for (int i = 0; i < 8; ++i)
#pragma unroll
            for (int j = 0; j < 8; ++j) {
                int ci = c0 + (j >> 2) * 64 + tx * 4 + (j & 3);
                ins5(acc[i][j], ci, t5v[i], t5i[i]);
            }
    }

    // merge 16 per-thread lists per row; rows: (i>>2)*64 + ty*4 + (i&3)
    float* mv = smem;
    int*   mi = (int*)(smem + 64 * 81);
    for (int g = 0; g < 2; ++g) {
        __syncthreads();
#pragma unroll
        for (int i = 0; i < 4; ++i)
#pragma unroll
            for (int k = 0; k < KTOP; ++k) {
                mv[(ty * 4 + i) * 81 + tx * 5 + k] = t5v[g * 4 + i][k];
                mi[(ty * 4 + i) * 81 + tx * 5 + k] = t5i[g * 4 + i][k];
            }
        __syncthreads();
        if (t < 64) {
            float pvL = INFINITY; int piL = -1;
            for (int k = 0; k < KTOP; ++k) {
                float bv = -INFINITY; int bi = 0x7fffffff;
                for (int n = 0; n < 80; ++n) {
                    float v = mv[t * 81 + n];
                    int   x = mi[t * 81 + n];
                    bool worse_prev  = (v < pvL) || (v == pvL && x > piL);
                    bool better_best = (v > bv)  || (v == bv  && x < bi);
                    if (worse_prev && better_best) { bv = v; bi = x; }
                }
                int o = ((r0 + g * 64 + t) * SPLITS + s) * KTOP + k;
                pval[o] = bv; pidx[o] = bi;
                pvL = bv; piL = bi;
            }
        }
    }
}

// ================================================================ fused final-merge + attention
__global__ __launch_bounds__(TPB) void attn_kernel(
        const float* __restrict__ Qa, const float* __restrict__ Ka, const float* __restrict__ Va,
        const float* __restrict__ pval, const int* __restrict__ pidx, float* __restrict__ out) {
    int wv = threadIdx.x >> 6, lane = threadIdx.x & 63;
    int r = blockIdx.x * 4 + wv;
    const float* pv = pval + r * SPLITS * KTOP;    // 80 entries
    const int*   pi = pidx + r * SPLITS * KTOP;
    float v0 = pv[lane];            int i0 = pi[lane];
    float v1 = (lane < 16) ? pv[64 + lane] : -INFINITY;
    int   i1 = (lane < 16) ? pi[64 + lane] : 0x7fffffff;

    float prevv = INFINITY; int previ = -1;
    int cI[KTOP];
#pragma unroll
    for (int k = 0; k < KTOP; ++k) {
        bool adm0 = (v0 < prevv) || (v0 == prevv && i0 > previ);
        bool adm1 = (v1 < prevv) || (v1 == prevv && i1 > previ);
        float bv = adm0 ? v0 : -INFINITY;
        int   bi = adm0 ? i0 : 0x7fffffff;
        if (adm1 && (v1 > bv || (v1 == bv && i1 < bi))) { bv = v1; bi = i1; }
#pragma unroll
        for (int off = 1; off < 64; off <<= 1) {
            float ov = __shfl_xor(bv, off, 64);
            int   oi = __shfl_xor(bi, off, 64);
            if (ov > bv || (ov == bv && oi < bi)) { bv = ov; bi = oi; }
        }
        cI[k] = bi; prevv = bv; previ = bi;
    }

    float4 q = *(const float4*)&Qa[r * DQK + lane * 4];
    float sc[KTOP];
#pragma unroll
    for (int k = 0; k < KTOP; ++k) {
        float4 kk = *(const float4*)&Ka[cI[k] * DQK + lane * 4];
        float p = q.x * kk.x + q.y * kk.y + q.z * kk.z + q.w * kk.w;
#pragma unroll
        for (int off = 32; off; off >>= 1) p += __shfl_xor(p, off, 64);
        sc[k] = p * 0.0625f;   // 1/sqrt(256)
    }
    float m = sc[0];
#pragma unroll
    for (int k = 1; k < KTOP; ++k) m = fmaxf(m, sc[k]);
    float w[KTOP], ssum = 0.f;
#pragma unroll
    for (int k = 0; k < KTOP; ++k) { w[k] = expf(sc[k] - m); ssum += w[k]; }
    float inv = 1.f / ssum;
    float4 o = make_float4(0.f, 0.f, 0.f, 0.f);
#pragma unroll
    for (int k = 0; k < KTOP; ++k) {
        float4 vv = *(const float4*)&Va[cI[k] * DQK + lane * 4];
        float a = w[k] * inv;
        o.x = fmaf(a, vv.x, o.x); o.y = fmaf(a, vv.y, o.y);
        o.z = fmaf(a, vv.z, o.z); o.w = fmaf(a, vv.w, o.w);
    }
    *(float4*)&out[r * DQK + lane * 4] = o;
}

// ================================================================ launch
extern "C" void kernel_launch(void* const* d_in, const int* in_sizes, int n_in,
                              void* d_out, int out_size, void* d_ws, size_t ws_size,
                              hipStream_t stream) {
    const float* user  = (const float*)d_in[0];
    const float* item  = (const float*)d_in[1];
    const int*   nrows = (const int*)d_in[2];
    const int*   ncols = (const int*)d_in[3];
    const float* nvals = (const float*)d_in[4];
    const int*   arows = (const int*)d_in[5];
    const int*   acols = (const int*)d_in[6];
    const float* avals = (const float*)d_in[7];
    const float* Wq = (const float*)d_in[8];  const float* bq = (const float*)d_in[9];
    const float* Wk = (const float*)d_in[10]; const float* bk = (const float*)d_in[11];
    const float* Wv = (const float*)d_in[12]; const float* bv = (const float*)d_in[13];
    float* out = (float*)d_out;
    float* ws  = (float*)d_ws;

    const int NE  = NN * EDIM;             // 393216
    const int NQK = NN * DQK;              // 1572864
    float* ego1 = ws;
    float* ego2 = ws + NE;
    float* Qm   = ws + 2 * NE;
    float* Qa   = ws + 3 * NE;
    float* Ka   = Qa + NQK;
    float* Va   = Ka + NQK;
    float* pval = Va + NQK;
    int*   pidx = (int*)(pval + NN * SPLITS * KTOP);

    // CSR scratch aliased over Qa..Va (dead until qkv_gemm)
    int* csr     = (int*)Qa;
    int* cnt_n   = csr;
    int* cnt_a   = csr + 6144;
    int* start_n = csr + 12288;            // 6145
    int* start_a = csr + 18433;            // 6145
    int* cur_n   = csr + 24578;
    int* cur_a   = csr + 30722;
    int2* cv_n   = (int2*)(csr + 36866);
    int2* cv_a   = cv_n + NNZ;

    CoopParams cp;
    cp.user = user; cp.item = item;
    cp.nrows = nrows; cp.ncols = ncols; cp.nvals = nvals;
    cp.arows = arows; cp.acols = acols; cp.avals = avals;
    cp.cnt_n = cnt_n; cp.cnt_a = cnt_a;
    cp.start_n = start_n; cp.start_a = start_a;
    cp.cur_n = cur_n; cp.cur_a = cur_a;
    cp.cv_n = cv_n; cp.cv_a = cv_a;
    cp.ego1 = ego1; cp.ego2 = ego2; cp.Qm = Qm; cp.outmean = out;

    void* args[] = { &cp };
    hipLaunchCooperativeKernel((void*)gnn_coop_kernel, dim3(512), dim3(TPB), args, 0, stream);

    qkv_gemm_kernel<<<dim3(NN / 64, DQK / 128, 3), TPB, 0, stream>>>(ego2, Wq, bq, Wk, bk, Wv, bv,
                                                                     Qa, Ka, Va);
    topk_partial_kernel<<<dim3(NN / 128, SPLITS), TPB, 0, stream>>>(Qm, ego2, pval, pidx);
    attn_kernel<<<NN / 4, TPB, 0, stream>>>(Qa, Ka, Va, pval, pidx, out + NE);
}

// Round 4
// 400.747 us; speedup vs baseline: 2.4884x; 2.4884x over previous
//
#include <hip/hip_runtime.h>
#include <math.h>

#define NUSER 2560
#define NITEM 3584
#define NN    6144
#define EDIM  64
#define NNZ   200000
#define DQK   256
#define KTOP  5
#define SPLITS 16
#define TPS    3          // 48 cand tiles / 16 splits
#define TPB   256

// ================================================================ CSR build
__global__ void hist_kernel(const int* __restrict__ nr, const int* __restrict__ ar,
                            int* __restrict__ cnt_n, int* __restrict__ cnt_a) {
    int g = blockIdx.x * TPB + threadIdx.x;
    if (g < NNZ) atomicAdd(&cnt_n[nr[g]], 1);
    else if (g < 2 * NNZ) atomicAdd(&cnt_a[ar[g - NNZ]], 1);
}

__global__ void scan_kernel(const int* __restrict__ cnt_n, const int* __restrict__ cnt_a,
                            int* __restrict__ start_n, int* __restrict__ start_a,
                            int* __restrict__ cur_n, int* __restrict__ cur_a) {
    const int* cnt = blockIdx.x ? cnt_a : cnt_n;
    int* start = blockIdx.x ? start_a : start_n;
    int* cur   = blockIdx.x ? cur_a   : cur_n;
    __shared__ int sc[1024];
    int t = threadIdx.x;
    int loc[6]; int p = 0;
#pragma unroll
    for (int j = 0; j < 6; ++j) { loc[j] = cnt[t * 6 + j]; p += loc[j]; }
    sc[t] = p; __syncthreads();
    for (int off = 1; off < 1024; off <<= 1) {
        int v = (t >= off) ? sc[t - off] : 0;
        __syncthreads();
        sc[t] += v;
        __syncthreads();
    }
    int base = sc[t] - p;   // exclusive
#pragma unroll
    for (int j = 0; j < 6; ++j) { start[t * 6 + j] = base; cur[t * 6 + j] = base; base += loc[j]; }
    if (t == 1023) start[6144] = base;
}

__global__ void scatter_kernel(const int* __restrict__ nr, const int* __restrict__ nc,
                               const float* __restrict__ nv,
                               const int* __restrict__ ar, const int* __restrict__ ac,
                               const float* __restrict__ av,
                               int* __restrict__ cur_n, int* __restrict__ cur_a,
                               int2* __restrict__ cv_n, int2* __restrict__ cv_a) {
    int g = blockIdx.x * TPB + threadIdx.x;
    if (g < NNZ) {
        int pos = atomicAdd(&cur_n[nr[g]], 1);
        cv_n[pos] = make_int2(nc[g], __float_as_int(nv[g]));
    } else if (g < 2 * NNZ) {
        int h = g - NNZ;
        int pos = atomicAdd(&cur_a[ar[h]], 1);
        cv_a[pos] = make_int2(ac[h], __float_as_int(av[h]));
    }
}

// ================================================================ CSR SpMM, wave-per-row, x4 unroll (ILP)
__global__ __launch_bounds__(TPB) void spmm_csr_emb_kernel(
        const int* __restrict__ start, const int2* __restrict__ cv,
        const float* __restrict__ user, const float* __restrict__ item,
        float* __restrict__ dst) {
    int r = blockIdx.x * 4 + (threadIdx.x >> 6);
    int lane = threadIdx.x & 63;
    int s = start[r], e = start[r + 1];
    float a0 = 0.f, a1 = 0.f, a2 = 0.f, a3 = 0.f;
    int j = s, n4 = s + ((e - s) & ~3);
    for (; j < n4; j += 4) {
        int2 c0 = cv[j], c1 = cv[j + 1], c2 = cv[j + 2], c3 = cv[j + 3];
        float x0 = (c0.x < NUSER) ? user[c0.x * EDIM + lane] : item[(c0.x - NUSER) * EDIM + lane];
        float x1 = (c1.x < NUSER) ? user[c1.x * EDIM + lane] : item[(c1.x - NUSER) * EDIM + lane];
        float x2 = (c2.x < NUSER) ? user[c2.x * EDIM + lane] : item[(c2.x - NUSER) * EDIM + lane];
        float x3 = (c3.x < NUSER) ? user[c3.x * EDIM + lane] : item[(c3.x - NUSER) * EDIM + lane];
        a0 = fmaf(__int_as_float(c0.y), x0, a0);
        a1 = fmaf(__int_as_float(c1.y), x1, a1);
        a2 = fmaf(__int_as_float(c2.y), x2, a2);
        a3 = fmaf(__int_as_float(c3.y), x3, a3);
    }
    for (; j < e; ++j) {
        int2 c = cv[j];
        float x = (c.x < NUSER) ? user[c.x * EDIM + lane] : item[(c.x - NUSER) * EDIM + lane];
        a0 = fmaf(__int_as_float(c.y), x, a0);
    }
    dst[r * EDIM + lane] = (a0 + a1) + (a2 + a3);
}

__global__ __launch_bounds__(TPB) void spmm_csr_kernel(
        const int* __restrict__ start, const int2* __restrict__ cv,
        const float* __restrict__ src, float* __restrict__ dst) {
    int r = blockIdx.x * 4 + (threadIdx.x >> 6);
    int lane = threadIdx.x & 63;
    int s = start[r], e = start[r + 1];
    float a0 = 0.f, a1 = 0.f, a2 = 0.f, a3 = 0.f;
    int j = s, n4 = s + ((e - s) & ~3);
    for (; j < n4; j += 4) {
        int2 c0 = cv[j], c1 = cv[j + 1], c2 = cv[j + 2], c3 = cv[j + 3];
        float x0 = src[c0.x * EDIM + lane];
        float x1 = src[c1.x * EDIM + lane];
        float x2 = src[c2.x * EDIM + lane];
        float x3 = src[c3.x * EDIM + lane];
        a0 = fmaf(__int_as_float(c0.y), x0, a0);
        a1 = fmaf(__int_as_float(c1.y), x1, a1);
        a2 = fmaf(__int_as_float(c2.y), x2, a2);
        a3 = fmaf(__int_as_float(c3.y), x3, a3);
    }
    for (; j < e; ++j) {
        int2 c = cv[j];
        a0 = fmaf(__int_as_float(c.y), src[c.x * EDIM + lane], a0);
    }
    dst[r * EDIM + lane] = (a0 + a1) + (a2 + a3);
}

// Qm = ego2 + 0.5*(A@ego2) ; outmean = 0.5*(ego0+ego1)
__global__ __launch_bounds__(TPB) void qm_mean_kernel(
        const int* __restrict__ start, const int2* __restrict__ cv,
        const float* __restrict__ ego2, const float* __restrict__ ego1,
        const float* __restrict__ user, const float* __restrict__ item,
        float* __restrict__ Qm, float* __restrict__ outmean) {
    int r = blockIdx.x * 4 + (threadIdx.x >> 6);
    int lane = threadIdx.x & 63;
    int s = start[r], e = start[r + 1];
    float a0 = 0.f, a1 = 0.f, a2 = 0.f, a3 = 0.f;
    int j = s, n4 = s + ((e - s) & ~3);
    for (; j < n4; j += 4) {
        int2 c0 = cv[j], c1 = cv[j + 1], c2 = cv[j + 2], c3 = cv[j + 3];
        float x0 = ego2[c0.x * EDIM + lane];
        float x1 = ego2[c1.x * EDIM + lane];
        float x2 = ego2[c2.x * EDIM + lane];
        float x3 = ego2[c3.x * EDIM + lane];
        a0 = fmaf(__int_as_float(c0.y), x0, a0);
        a1 = fmaf(__int_as_float(c1.y), x1, a1);
        a2 = fmaf(__int_as_float(c2.y), x2, a2);
        a3 = fmaf(__int_as_float(c3.y), x3, a3);
    }
    for (; j < e; ++j) {
        int2 c = cv[j];
        a0 = fmaf(__int_as_float(c.y), ego2[c.x * EDIM + lane], a0);
    }
    float acc = (a0 + a1) + (a2 + a3);
    int o = r * EDIM + lane;
    Qm[o] = ego2[o] + 0.5f * acc;
    float e0v = (r < NUSER) ? user[o] : item[o - NUSER * EDIM];
    outmean[o] = 0.5f * (e0v + ego1[o]);
}

// ================================================================ QKV GEMM (validated)
__global__ __launch_bounds__(TPB, 3) void qkv_gemm_kernel(
        const float* __restrict__ A,
        const float* __restrict__ Wq, const float* __restrict__ bq,
        const float* __restrict__ Wk, const float* __restrict__ bk,
        const float* __restrict__ Wv, const float* __restrict__ bv,
        float* __restrict__ Qa, float* __restrict__ Ka, float* __restrict__ Va) {
    const float* W; const float* b; float* out;
    if (blockIdx.z == 0)      { W = Wq; b = bq; out = Qa; }
    else if (blockIdx.z == 1) { W = Wk; b = bk; out = Ka; }
    else                      { W = Wv; b = bv; out = Va; }

    __shared__ __align__(16) float smem[64 * 64 + 128 * 64];
    float* As = smem;
    float* Bs = smem + 4096;
    int t = threadIdx.x, tx = t & 15, ty = t >> 4;
    int r0 = blockIdx.x * 64, d0 = blockIdx.y * 128;

    {
        int r = t & 63, eb = (t >> 6) * 16;
#pragma unroll
        for (int rep = 0; rep < 4; ++rep) {
            int e0 = eb + rep * 4;
            float4 v = *(const float4*)&A[(r0 + r) * EDIM + e0];
            As[(e0 + 0) * 64 + r] = v.x; As[(e0 + 1) * 64 + r] = v.y;
            As[(e0 + 2) * 64 + r] = v.z; As[(e0 + 3) * 64 + r] = v.w;
        }
    }
    {
        int d = t & 127, eb = (t >> 7) * 32;
#pragma unroll
        for (int rep = 0; rep < 8; ++rep) {
            int e0 = eb + rep * 4;
            float4 v = *(const float4*)&W[(d0 + d) * EDIM + e0];
            Bs[(e0 + 0) * 128 + d] = v.x; Bs[(e0 + 1) * 128 + d] = v.y;
            Bs[(e0 + 2) * 128 + d] = v.z; Bs[(e0 + 3) * 128 + d] = v.w;
        }
    }
    __syncthreads();

    float acc[4][8];
#pragma unroll
    for (int i = 0; i < 4; ++i)
#pragma unroll
        for (int j = 0; j < 8; ++j) acc[i][j] = 0.f;

#pragma unroll 4
    for (int e = 0; e < 64; ++e) {
        float4 a  = *(const float4*)&As[e * 64 + ty * 4];
        float4 b0 = *(const float4*)&Bs[e * 128 + tx * 4];
        float4 b1 = *(const float4*)&Bs[e * 128 + 64 + tx * 4];
        float ar[4] = {a.x, a.y, a.z, a.w};
#pragma unroll
        for (int i = 0; i < 4; ++i) {
            acc[i][0] = fmaf(ar[i], b0.x, acc[i][0]);
            acc[i][1] = fmaf(ar[i], b0.y, acc[i][1]);
            acc[i][2] = fmaf(ar[i], b0.z, acc[i][2]);
            acc[i][3] = fmaf(ar[i], b0.w, acc[i][3]);
            acc[i][4] = fmaf(ar[i], b1.x, acc[i][4]);
            acc[i][5] = fmaf(ar[i], b1.y, acc[i][5]);
            acc[i][6] = fmaf(ar[i], b1.z, acc[i][6]);
            acc[i][7] = fmaf(ar[i], b1.w, acc[i][7]);
        }
    }
    float4 bias0 = *(const float4*)&b[d0 + tx * 4];
    float4 bias1 = *(const float4*)&b[d0 + 64 + tx * 4];
#pragma unroll
    for (int i = 0; i < 4; ++i) {
        int r = r0 + ty * 4 + i;
        float4 o0 = make_float4(acc[i][0] + bias0.x, acc[i][1] + bias0.y,
                                acc[i][2] + bias0.z, acc[i][3] + bias0.w);
        float4 o1 = make_float4(acc[i][4] + bias1.x, acc[i][5] + bias1.y,
                                acc[i][6] + bias1.z, acc[i][7] + bias1.w);
        *(float4*)&out[r * DQK + d0 + tx * 4] = o0;
        *(float4*)&out[r * DQK + d0 + 64 + tx * 4] = o1;
    }
}

// ================================================================ fused sim top-5 (8x8 microtile, both LDS)
__device__ __forceinline__ void ins5(float v, int ci, float tv[KTOP], int ti[KTOP]) {
    if (v > tv[4]) {
#pragma unroll
        for (int k = 4; k >= 1; --k) {
            bool sh = v > tv[k];
            bool ph = v > tv[k - 1];
            float nv = ph ? tv[k - 1] : v;
            int   ni = ph ? ti[k - 1] : ci;
            if (sh) { tv[k] = nv; ti[k] = ni; }
        }
        if (v > tv[0]) { tv[0] = v; ti[0] = ci; }
    }
}

__global__ __launch_bounds__(TPB, 2) void topk_partial_kernel(
        const float* __restrict__ Qm, const float* __restrict__ P,
        float* __restrict__ pval, int* __restrict__ pidx) {
    __shared__ __align__(16) float smem[16384];   // 64 KB: Qs[64][128] + Ps[64][128]
    float* Qs = smem;
    float* Ps = smem + 8192;
    int t = threadIdx.x, tx = t & 15, ty = t >> 4;
    int r0 = blockIdx.x * 128;
    int s  = blockIdx.y;

    { // stage Q transposed (once per block)
        int r = t & 127, q = t >> 7;
#pragma unroll
        for (int rep = 0; rep < 8; ++rep) {
            int e = q * 32 + rep * 4;
            float4 v = *(const float4*)&Qm[(r0 + r) * EDIM + e];
            Qs[(e + 0) * 128 + r] = v.x;
            Qs[(e + 1) * 128 + r] = v.y;
            Qs[(e + 2) * 128 + r] = v.z;
            Qs[(e + 3) * 128 + r] = v.w;
        }
    }

    float t5v[8][KTOP]; int t5i[8][KTOP];
#pragma unroll
    for (int i = 0; i < 8; ++i)
#pragma unroll
        for (int k = 0; k < KTOP; ++k) { t5v[i][k] = -INFINITY; t5i[i][k] = 0x7fffffff; }

    for (int tile = 0; tile < TPS; ++tile) {
        int c0 = (s * TPS + tile) * 128;
        __syncthreads();
        { // stage P tile transposed
            int c = t & 127, q = t >> 7;
#pragma unroll
            for (int rep = 0; rep < 8; ++rep) {
                int e = q * 32 + rep * 4;
                float4 v = *(const float4*)&P[(c0 + c) * EDIM + e];
                Ps[(e + 0) * 128 + c] = v.x;
                Ps[(e + 1) * 128 + c] = v.y;
                Ps[(e + 2) * 128 + c] = v.z;
                Ps[(e + 3) * 128 + c] = v.w;
            }
        }
        __syncthreads();

        float acc[8][8];
#pragma unroll
        for (int i = 0; i < 8; ++i)
#pragma unroll
            for (int j = 0; j < 8; ++j) acc[i][j] = 0.f;

#pragma unroll 2
        for (int e = 0; e < 64; ++e) {
            float4 a0 = *(const float4*)&Qs[e * 128 + ty * 4];
            float4 a1 = *(const float4*)&Qs[e * 128 + 64 + ty * 4];
            float4 b0 = *(const float4*)&Ps[e * 128 + tx * 4];
            float4 b1 = *(const float4*)&Ps[e * 128 + 64 + tx * 4];
            float ar[8] = {a0.x, a0.y, a0.z, a0.w, a1.x, a1.y, a1.z, a1.w};
            float br[8] = {b0.x, b0.y, b0.z, b0.w, b1.x, b1.y, b1.z, b1.w};
#pragma unroll
            for (int i = 0; i < 8; ++i)
#pragma unroll
                for (int j = 0; j < 8; ++j)
                    acc[i][j] = fmaf(ar[i], br[j], acc[i][j]);
        }

#pragma unroll
        for (int i = 0; i < 8; ++i)
#pragma unroll
            for (int j = 0; j < 8; ++j) {
                int ci = c0 + (j >> 2) * 64 + tx * 4 + (j & 3);
                ins5(acc[i][j], ci, t5v[i], t5i[i]);
            }
    }

    // merge 16 per-thread lists per row
    float* mv = smem;
    int*   mi = (int*)(smem + 64 * 81);
    for (int g = 0; g < 2; ++g) {
        __syncthreads();
#pragma unroll
        for (int i = 0; i < 4; ++i)
#pragma unroll
            for (int k = 0; k < KTOP; ++k) {
                mv[(ty * 4 + i) * 81 + tx * 5 + k] = t5v[g * 4 + i][k];
                mi[(ty * 4 + i) * 81 + tx * 5 + k] = t5i[g * 4 + i][k];
            }
        __syncthreads();
        if (t < 64) {
            float pvL = INFINITY; int piL = -1;
            for (int k = 0; k < KTOP; ++k) {
                float bv = -INFINITY; int bi = 0x7fffffff;
                for (int n = 0; n < 80; ++n) {
                    float v = mv[t * 81 + n];
                    int   x = mi[t * 81 + n];
                    bool worse_prev  = (v < pvL) || (v == pvL && x > piL);
                    bool better_best = (v > bv)  || (v == bv  && x < bi);
                    if (worse_prev && better_best) { bv = v; bi = x; }
                }
                int o = ((r0 + g * 64 + t) * SPLITS + s) * KTOP + k;
                pval[o] = bv; pidx[o] = bi;
                pvL = bv; piL = bi;
            }
        }
    }
}

// ================================================================ fused final-merge + attention
__global__ __launch_bounds__(TPB) void attn_kernel(
        const float* __restrict__ Qa, const float* __restrict__ Ka, const float* __restrict__ Va,
        const float* __restrict__ pval, const int* __restrict__ pidx, float* __restrict__ out) {
    int wv = threadIdx.x >> 6, lane = threadIdx.x & 63;
    int r = blockIdx.x * 4 + wv;
    const float* pv = pval + r * SPLITS * KTOP;    // 80 entries
    const int*   pi = pidx + r * SPLITS * KTOP;
    float v0 = pv[lane];            int i0 = pi[lane];
    float v1 = (lane < 16) ? pv[64 + lane] : -INFINITY;
    int   i1 = (lane < 16) ? pi[64 + lane] : 0x7fffffff;

    float prevv = INFINITY; int previ = -1;
    int cI[KTOP];
#pragma unroll
    for (int k = 0; k < KTOP; ++k) {
        bool adm0 = (v0 < prevv) || (v0 == prevv && i0 > previ);
        bool adm1 = (v1 < prevv) || (v1 == prevv && i1 > previ);
        float bv = adm0 ? v0 : -INFINITY;
        int   bi = adm0 ? i0 : 0x7fffffff;
        if (adm1 && (v1 > bv || (v1 == bv && i1 < bi))) { bv = v1; bi = i1; }
#pragma unroll
        for (int off = 1; off < 64; off <<= 1) {
            float ov = __shfl_xor(bv, off, 64);
            int   oi = __shfl_xor(bi, off, 64);
            if (ov > bv || (ov == bv && oi < bi)) { bv = ov; bi = oi; }
        }
        cI[k] = bi; prevv = bv; previ = bi;
    }

    float4 q = *(const float4*)&Qa[r * DQK + lane * 4];
    float sc[KTOP];
#pragma unroll
    for (int k = 0; k < KTOP; ++k) {
        float4 kk = *(const float4*)&Ka[cI[k] * DQK + lane * 4];
        float p = q.x * kk.x + q.y * kk.y + q.z * kk.z + q.w * kk.w;
#pragma unroll
        for (int off = 32; off; off >>= 1) p += __shfl_xor(p, off, 64);
        sc[k] = p * 0.0625f;   // 1/sqrt(256)
    }
    float m = sc[0];
#pragma unroll
    for (int k = 1; k < KTOP; ++k) m = fmaxf(m, sc[k]);
    float w[KTOP], ssum = 0.f;
#pragma unroll
    for (int k = 0; k < KTOP; ++k) { w[k] = expf(sc[k] - m); ssum += w[k]; }
    float inv = 1.f / ssum;
    float4 o = make_float4(0.f, 0.f, 0.f, 0.f);
#pragma unroll
    for (int k = 0; k < KTOP; ++k) {
        float4 vv = *(const float4*)&Va[cI[k] * DQK + lane * 4];
        float a = w[k] * inv;
        o.x = fmaf(a, vv.x, o.x); o.y = fmaf(a, vv.y, o.y);
        o.z = fmaf(a, vv.z, o.z); o.w = fmaf(a, vv.w, o.w);
    }
    *(float4*)&out[r * DQK + lane * 4] = o;
}

// ================================================================ launch
extern "C" void kernel_launch(void* const* d_in, const int* in_sizes, int n_in,
                              void* d_out, int out_size, void* d_ws, size_t ws_size,
                              hipStream_t stream) {
    const float* user  = (const float*)d_in[0];
    const float* item  = (const float*)d_in[1];
    const int*   nrows = (const int*)d_in[2];
    const int*   ncols = (const int*)d_in[3];
    const float* nvals = (const float*)d_in[4];
    const int*   arows = (const int*)d_in[5];
    const int*   acols = (const int*)d_in[6];
    const float* avals = (const float*)d_in[7];
    const float* Wq = (const float*)d_in[8];  const float* bq = (const float*)d_in[9];
    const float* Wk = (const float*)d_in[10]; const float* bk = (const float*)d_in[11];
    const float* Wv = (const float*)d_in[12]; const float* bv = (const float*)d_in[13];
    float* out = (float*)d_out;
    float* ws  = (float*)d_ws;

    const int NE  = NN * EDIM;             // 393216
    const int NQK = NN * DQK;              // 1572864
    float* ego1 = ws;
    float* ego2 = ws + NE;
    float* Qm   = ws + 2 * NE;
    float* Qa   = ws + 3 * NE;
    float* Ka   = Qa + NQK;
    float* Va   = Ka + NQK;
    float* pval = Va + NQK;
    int*   pidx = (int*)(pval + NN * SPLITS * KTOP);

    // CSR scratch aliased over Qa..Va (dead until qkv_gemm)
    int* csr     = (int*)Qa;
    int* cnt_n   = csr;
    int* cnt_a   = csr + 6144;
    int* start_n = csr + 12288;            // 6145
    int* start_a = csr + 18433;            // 6145
    int* cur_n   = csr + 24578;
    int* cur_a   = csr + 30722;
    int2* cv_n   = (int2*)(csr + 36866);
    int2* cv_a   = cv_n + NNZ;

    // zero histograms (graph-capture-legal memset node)
    hipMemsetAsync(cnt_n, 0, 12288 * sizeof(int), stream);
    hist_kernel<<<(2 * NNZ + TPB - 1) / TPB, TPB, 0, stream>>>(nrows, arows, cnt_n, cnt_a);
    scan_kernel<<<2, 1024, 0, stream>>>(cnt_n, cnt_a, start_n, start_a, cur_n, cur_a);
    scatter_kernel<<<(2 * NNZ + TPB - 1) / TPB, TPB, 0, stream>>>(nrows, ncols, nvals,
                                                                  arows, acols, avals,
                                                                  cur_n, cur_a, cv_n, cv_a);
    spmm_csr_emb_kernel<<<NN / 4, TPB, 0, stream>>>(start_n, cv_n, user, item, ego1);
    spmm_csr_kernel<<<NN / 4, TPB, 0, stream>>>(start_n, cv_n, ego1, ego2);
    qm_mean_kernel<<<NN / 4, TPB, 0, stream>>>(start_a, cv_a, ego2, ego1, user, item, Qm, out);
    qkv_gemm_kernel<<<dim3(NN / 64, DQK / 128, 3), TPB, 0, stream>>>(ego2, Wq, bq, Wk, bk, Wv, bv,
                                                                     Qa, Ka, Va);
    topk_partial_kernel<<<dim3(NN / 128, SPLITS), TPB, 0, stream>>>(Qm, ego2, pval, pidx);
    attn_kernel<<<NN / 4, TPB, 0, stream>>>(Qa, Ka, Va, pval, pidx, out + NE);
}

// Round 5
// 277.659 us; speedup vs baseline: 3.5915x; 1.4433x over previous
//
#include <hip/hip_runtime.h>
#include <math.h>

#define NUSER 2560
#define NITEM 3584
#define NN    6144
#define EDIM  64
#define NNZ   200000
#define DQK   256
#define KTOP  5
#define SPLITS 16
#define TPS    3          // 48 cand tiles / 16 splits
#define TPB   256

// ================================================================ CSR build
__global__ void hist_kernel(const int* __restrict__ nr, const int* __restrict__ ar,
                            int* __restrict__ cnt_n, int* __restrict__ cnt_a) {
    int g = blockIdx.x * TPB + threadIdx.x;
    if (g < NNZ) atomicAdd(&cnt_n[nr[g]], 1);
    else if (g < 2 * NNZ) atomicAdd(&cnt_a[ar[g - NNZ]], 1);
}

__global__ void scan_kernel(const int* __restrict__ cnt_n, const int* __restrict__ cnt_a,
                            int* __restrict__ start_n, int* __restrict__ start_a,
                            int* __restrict__ cur_n, int* __restrict__ cur_a) {
    const int* cnt = blockIdx.x ? cnt_a : cnt_n;
    int* start = blockIdx.x ? start_a : start_n;
    int* cur   = blockIdx.x ? cur_a   : cur_n;
    __shared__ int sc[1024];
    int t = threadIdx.x;
    int loc[6]; int p = 0;
#pragma unroll
    for (int j = 0; j < 6; ++j) { loc[j] = cnt[t * 6 + j]; p += loc[j]; }
    sc[t] = p; __syncthreads();
    for (int off = 1; off < 1024; off <<= 1) {
        int v = (t >= off) ? sc[t - off] : 0;
        __syncthreads();
        sc[t] += v;
        __syncthreads();
    }
    int base = sc[t] - p;   // exclusive
#pragma unroll
    for (int j = 0; j < 6; ++j) { start[t * 6 + j] = base; cur[t * 6 + j] = base; base += loc[j]; }
    if (t == 1023) start[6144] = base;
}

__global__ void scatter_kernel(const int* __restrict__ nr, const int* __restrict__ nc,
                               const float* __restrict__ nv,
                               const int* __restrict__ ar, const int* __restrict__ ac,
                               const float* __restrict__ av,
                               int* __restrict__ cur_n, int* __restrict__ cur_a,
                               int2* __restrict__ cv_n, int2* __restrict__ cv_a) {
    int g = blockIdx.x * TPB + threadIdx.x;
    if (g < NNZ) {
        int pos = atomicAdd(&cur_n[nr[g]], 1);
        cv_n[pos] = make_int2(nc[g], __float_as_int(nv[g]));
    } else if (g < 2 * NNZ) {
        int h = g - NNZ;
        int pos = atomicAdd(&cur_a[ar[h]], 1);
        cv_a[pos] = make_int2(ac[h], __float_as_int(av[h]));
    }
}

// ================================================================ CSR SpMM, wave-per-row, x4 unroll (ILP)
__global__ __launch_bounds__(TPB) void spmm_csr_emb_kernel(
        const int* __restrict__ start, const int2* __restrict__ cv,
        const float* __restrict__ user, const float* __restrict__ item,
        float* __restrict__ dst) {
    int r = blockIdx.x * 4 + (threadIdx.x >> 6);
    int lane = threadIdx.x & 63;
    int s = start[r], e = start[r + 1];
    float a0 = 0.f, a1 = 0.f, a2 = 0.f, a3 = 0.f;
    int j = s, n4 = s + ((e - s) & ~3);
    for (; j < n4; j += 4) {
        int2 c0 = cv[j], c1 = cv[j + 1], c2 = cv[j + 2], c3 = cv[j + 3];
        float x0 = (c0.x < NUSER) ? user[c0.x * EDIM + lane] : item[(c0.x - NUSER) * EDIM + lane];
        float x1 = (c1.x < NUSER) ? user[c1.x * EDIM + lane] : item[(c1.x - NUSER) * EDIM + lane];
        float x2 = (c2.x < NUSER) ? user[c2.x * EDIM + lane] : item[(c2.x - NUSER) * EDIM + lane];
        float x3 = (c3.x < NUSER) ? user[c3.x * EDIM + lane] : item[(c3.x - NUSER) * EDIM + lane];
        a0 = fmaf(__int_as_float(c0.y), x0, a0);
        a1 = fmaf(__int_as_float(c1.y), x1, a1);
        a2 = fmaf(__int_as_float(c2.y), x2, a2);
        a3 = fmaf(__int_as_float(c3.y), x3, a3);
    }
    for (; j < e; ++j) {
        int2 c = cv[j];
        float x = (c.x < NUSER) ? user[c.x * EDIM + lane] : item[(c.x - NUSER) * EDIM + lane];
        a0 = fmaf(__int_as_float(c.y), x, a0);
    }
    dst[r * EDIM + lane] = (a0 + a1) + (a2 + a3);
}

__global__ __launch_bounds__(TPB) void spmm_csr_kernel(
        const int* __restrict__ start, const int2* __restrict__ cv,
        const float* __restrict__ src, float* __restrict__ dst) {
    int r = blockIdx.x * 4 + (threadIdx.x >> 6);
    int lane = threadIdx.x & 63;
    int s = start[r], e = start[r + 1];
    float a0 = 0.f, a1 = 0.f, a2 = 0.f, a3 = 0.f;
    int j = s, n4 = s + ((e - s) & ~3);
    for (; j < n4; j += 4) {
        int2 c0 = cv[j], c1 = cv[j + 1], c2 = cv[j + 2], c3 = cv[j + 3];
        float x0 = src[c0.x * EDIM + lane];
        float x1 = src[c1.x * EDIM + lane];
        float x2 = src[c2.x * EDIM + lane];
        float x3 = src[c3.x * EDIM + lane];
        a0 = fmaf(__int_as_float(c0.y), x0, a0);
        a1 = fmaf(__int_as_float(c1.y), x1, a1);
        a2 = fmaf(__int_as_float(c2.y), x2, a2);
        a3 = fmaf(__int_as_float(c3.y), x3, a3);
    }
    for (; j < e; ++j) {
        int2 c = cv[j];
        a0 = fmaf(__int_as_float(c.y), src[c.x * EDIM + lane], a0);
    }
    dst[r * EDIM + lane] = (a0 + a1) + (a2 + a3);
}

// Qm = ego2 + 0.5*(A@ego2) ; outmean = 0.5*(ego0+ego1)
__global__ __launch_bounds__(TPB) void qm_mean_kernel(
        const int* __restrict__ start, const int2* __restrict__ cv,
        const float* __restrict__ ego2, const float* __restrict__ ego1,
        const float* __restrict__ user, const float* __restrict__ item,
        float* __restrict__ Qm, float* __restrict__ outmean) {
    int r = blockIdx.x * 4 + (threadIdx.x >> 6);
    int lane = threadIdx.x & 63;
    int s = start[r], e = start[r + 1];
    float a0 = 0.f, a1 = 0.f, a2 = 0.f, a3 = 0.f;
    int j = s, n4 = s + ((e - s) & ~3);
    for (; j < n4; j += 4) {
        int2 c0 = cv[j], c1 = cv[j + 1], c2 = cv[j + 2], c3 = cv[j + 3];
        float x0 = ego2[c0.x * EDIM + lane];
        float x1 = ego2[c1.x * EDIM + lane];
        float x2 = ego2[c2.x * EDIM + lane];
        float x3 = ego2[c3.x * EDIM + lane];
        a0 = fmaf(__int_as_float(c0.y), x0, a0);
        a1 = fmaf(__int_as_float(c1.y), x1, a1);
        a2 = fmaf(__int_as_float(c2.y), x2, a2);
        a3 = fmaf(__int_as_float(c3.y), x3, a3);
    }
    for (; j < e; ++j) {
        int2 c = cv[j];
        a0 = fmaf(__int_as_float(c.y), ego2[c.x * EDIM + lane], a0);
    }
    float acc = (a0 + a1) + (a2 + a3);
    int o = r * EDIM + lane;
    Qm[o] = ego2[o] + 0.5f * acc;
    float e0v = (r < NUSER) ? user[o] : item[o - NUSER * EDIM];
    outmean[o] = 0.5f * (e0v + ego1[o]);
}

// ================================================================ QKV GEMM (validated)
__global__ __launch_bounds__(TPB, 3) void qkv_gemm_kernel(
        const float* __restrict__ A,
        const float* __restrict__ Wq, const float* __restrict__ bq,
        const float* __restrict__ Wk, const float* __restrict__ bk,
        const float* __restrict__ Wv, const float* __restrict__ bv,
        float* __restrict__ Qa, float* __restrict__ Ka, float* __restrict__ Va) {
    const float* W; const float* b; float* out;
    if (blockIdx.z == 0)      { W = Wq; b = bq; out = Qa; }
    else if (blockIdx.z == 1) { W = Wk; b = bk; out = Ka; }
    else                      { W = Wv; b = bv; out = Va; }

    __shared__ __align__(16) float smem[64 * 64 + 128 * 64];
    float* As = smem;
    float* Bs = smem + 4096;
    int t = threadIdx.x, tx = t & 15, ty = t >> 4;
    int r0 = blockIdx.x * 64, d0 = blockIdx.y * 128;

    {
        int r = t & 63, eb = (t >> 6) * 16;
#pragma unroll
        for (int rep = 0; rep < 4; ++rep) {
            int e0 = eb + rep * 4;
            float4 v = *(const float4*)&A[(r0 + r) * EDIM + e0];
            As[(e0 + 0) * 64 + r] = v.x; As[(e0 + 1) * 64 + r] = v.y;
            As[(e0 + 2) * 64 + r] = v.z; As[(e0 + 3) * 64 + r] = v.w;
        }
    }
    {
        int d = t & 127, eb = (t >> 7) * 32;
#pragma unroll
        for (int rep = 0; rep < 8; ++rep) {
            int e0 = eb + rep * 4;
            float4 v = *(const float4*)&W[(d0 + d) * EDIM + e0];
            Bs[(e0 + 0) * 128 + d] = v.x; Bs[(e0 + 1) * 128 + d] = v.y;
            Bs[(e0 + 2) * 128 + d] = v.z; Bs[(e0 + 3) * 128 + d] = v.w;
        }
    }
    __syncthreads();

    float acc[4][8];
#pragma unroll
    for (int i = 0; i < 4; ++i)
#pragma unroll
        for (int j = 0; j < 8; ++j) acc[i][j] = 0.f;

#pragma unroll 4
    for (int e = 0; e < 64; ++e) {
        float4 a  = *(const float4*)&As[e * 64 + ty * 4];
        float4 b0 = *(const float4*)&Bs[e * 128 + tx * 4];
        float4 b1 = *(const float4*)&Bs[e * 128 + 64 + tx * 4];
        float ar[4] = {a.x, a.y, a.z, a.w};
#pragma unroll
        for (int i = 0; i < 4; ++i) {
            acc[i][0] = fmaf(ar[i], b0.x, acc[i][0]);
            acc[i][1] = fmaf(ar[i], b0.y, acc[i][1]);
            acc[i][2] = fmaf(ar[i], b0.z, acc[i][2]);
            acc[i][3] = fmaf(ar[i], b0.w, acc[i][3]);
            acc[i][4] = fmaf(ar[i], b1.x, acc[i][4]);
            acc[i][5] = fmaf(ar[i], b1.y, acc[i][5]);
            acc[i][6] = fmaf(ar[i], b1.z, acc[i][6]);
            acc[i][7] = fmaf(ar[i], b1.w, acc[i][7]);
        }
    }
    float4 bias0 = *(const float4*)&b[d0 + tx * 4];
    float4 bias1 = *(const float4*)&b[d0 + 64 + tx * 4];
#pragma unroll
    for (int i = 0; i < 4; ++i) {
        int r = r0 + ty * 4 + i;
        float4 o0 = make_float4(acc[i][0] + bias0.x, acc[i][1] + bias0.y,
                                acc[i][2] + bias0.z, acc[i][3] + bias0.w);
        float4 o1 = make_float4(acc[i][4] + bias1.x, acc[i][5] + bias1.y,
                                acc[i][6] + bias1.z, acc[i][7] + bias1.w);
        *(float4*)&out[r * DQK + d0 + tx * 4] = o0;
        *(float4*)&out[r * DQK + d0 + 64 + tx * 4] = o1;
    }
}

// ================================================================ fused sim top-5
// 64 rows x (TPS x 128 cands) per block; 4x8 microtile; both operands LDS; shuffle merge.
__device__ __forceinline__ void ins5(float v, int ci, float tv[KTOP], int ti[KTOP]) {
    if (v > tv[4]) {
#pragma unroll
        for (int k = 4; k >= 1; --k) {
            bool sh = v > tv[k];
            bool ph = v > tv[k - 1];
            float nv = ph ? tv[k - 1] : v;
            int   ni = ph ? ti[k - 1] : ci;
            if (sh) { tv[k] = nv; ti[k] = ni; }
        }
        if (v > tv[0]) { tv[0] = v; ti[0] = ci; }
    }
}

__global__ __launch_bounds__(TPB, 3) void topk_partial_kernel(
        const float* __restrict__ Qm, const float* __restrict__ P,
        float* __restrict__ pval, int* __restrict__ pidx) {
    __shared__ __align__(16) float smem[4096 + 8192];   // 48 KB: Qs[64e][64r] + Ps[64e][128c]
    float* Qs = smem;
    float* Ps = smem + 4096;
    int t = threadIdx.x, tx = t & 15, ty = t >> 4;
    int r0 = blockIdx.x * 64;
    int s  = blockIdx.y;

    { // stage Q transposed (once per block)
        int r = t & 63, eb = (t >> 6) * 16;
#pragma unroll
        for (int rep = 0; rep < 4; ++rep) {
            int e0 = eb + rep * 4;
            float4 v = *(const float4*)&Qm[(r0 + r) * EDIM + e0];
            Qs[(e0 + 0) * 64 + r] = v.x; Qs[(e0 + 1) * 64 + r] = v.y;
            Qs[(e0 + 2) * 64 + r] = v.z; Qs[(e0 + 3) * 64 + r] = v.w;
        }
    }

    float t5v[4][KTOP]; int t5i[4][KTOP];
#pragma unroll
    for (int i = 0; i < 4; ++i)
#pragma unroll
        for (int k = 0; k < KTOP; ++k) { t5v[i][k] = -INFINITY; t5i[i][k] = 0x7fffffff; }

    for (int tile = 0; tile < TPS; ++tile) {
        int c0 = (s * TPS + tile) * 128;
        __syncthreads();            // Ps consumed (and Qs ready on tile 0)
        { // stage P tile transposed
            int c = t & 127, eb = (t >> 7) * 32;
#pragma unroll
            for (int rep = 0; rep < 8; ++rep) {
                int e0 = eb + rep * 4;
                float4 v = *(const float4*)&P[(c0 + c) * EDIM + e0];
                Ps[(e0 + 0) * 128 + c] = v.x; Ps[(e0 + 1) * 128 + c] = v.y;
                Ps[(e0 + 2) * 128 + c] = v.z; Ps[(e0 + 3) * 128 + c] = v.w;
            }
        }
        __syncthreads();

        float acc[4][8];
#pragma unroll
        for (int i = 0; i < 4; ++i)
#pragma unroll
            for (int j = 0; j < 8; ++j) acc[i][j] = 0.f;

#pragma unroll 4
        for (int e = 0; e < 64; ++e) {
            float4 a  = *(const float4*)&Qs[e * 64 + ty * 4];
            float4 b0 = *(const float4*)&Ps[e * 128 + tx * 4];
            float4 b1 = *(const float4*)&Ps[e * 128 + 64 + tx * 4];
            float ar[4] = {a.x, a.y, a.z, a.w};
#pragma unroll
            for (int i = 0; i < 4; ++i) {
                acc[i][0] = fmaf(ar[i], b0.x, acc[i][0]);
                acc[i][1] = fmaf(ar[i], b0.y, acc[i][1]);
                acc[i][2] = fmaf(ar[i], b0.z, acc[i][2]);
                acc[i][3] = fmaf(ar[i], b0.w, acc[i][3]);
                acc[i][4] = fmaf(ar[i], b1.x, acc[i][4]);
                acc[i][5] = fmaf(ar[i], b1.y, acc[i][5]);
                acc[i][6] = fmaf(ar[i], b1.z, acc[i][6]);
                acc[i][7] = fmaf(ar[i], b1.w, acc[i][7]);
            }
        }

        // per-thread candidate order increasing in ci -> first-seen keeps lowest index on ties
#pragma unroll
        for (int i = 0; i < 4; ++i)
#pragma unroll
            for (int j = 0; j < 8; ++j) {
                int ci = c0 + (j >> 2) * 64 + tx * 4 + (j & 3);
                ins5(acc[i][j], ci, t5v[i], t5i[i]);
            }
    }

    // wave-shuffle merge: row (ty*4+i)'s 16 partial lists live in lanes (ty&3)*16 .. +15.
    // 5 rounds of admissible-argmax via 16-lane butterfly; no LDS, no barriers.
#pragma unroll
    for (int i = 0; i < 4; ++i) {
        int row = r0 + ty * 4 + i;
        int ptr = 0;
        for (int k = 0; k < KTOP; ++k) {
            float cvv; int cii;
            // manual 5-way select (avoid dynamic VGPR indexing)
            cvv = (ptr == 0) ? t5v[i][0] : (ptr == 1) ? t5v[i][1] : (ptr == 2) ? t5v[i][2]
                : (ptr == 3) ? t5v[i][3] : (ptr == 4) ? t5v[i][4] : -INFINITY;
            cii = (ptr == 0) ? t5i[i][0] : (ptr == 1) ? t5i[i][1] : (ptr == 2) ? t5i[i][2]
                : (ptr == 3) ? t5i[i][3] : (ptr == 4) ? t5i[i][4] : 0x7fffffff;
            float bv = cvv; int bi = cii;
#pragma unroll
            for (int off = 1; off < 16; off <<= 1) {
                float ov = __shfl_xor(bv, off, 64);
                int   oi = __shfl_xor(bi, off, 64);
                if (ov > bv || (ov == bv && oi < bi)) { bv = ov; bi = oi; }
            }
            if (bv == cvv && bi == cii) ptr++;   // my head was consumed
            if (tx == 0) {
                int o = (row * SPLITS + s) * KTOP + k;
                pval[o] = bv; pidx[o] = bi;
            }
        }
    }
}

// ================================================================ fused final-merge + attention
__global__ __launch_bounds__(TPB) void attn_kernel(
        const float* __restrict__ Qa, const float* __restrict__ Ka, const float* __restrict__ Va,
        const float* __restrict__ pval, const int* __restrict__ pidx, float* __restrict__ out) {
    int wv = threadIdx.x >> 6, lane = threadIdx.x & 63;
    int r = blockIdx.x * 4 + wv;
    const float* pv = pval + r * SPLITS * KTOP;    // 80 entries
    const int*   pi = pidx + r * SPLITS * KTOP;
    float v0 = pv[lane];            int i0 = pi[lane];
    float v1 = (lane < 16) ? pv[64 + lane] : -INFINITY;
    int   i1 = (lane < 16) ? pi[64 + lane] : 0x7fffffff;

    float prevv = INFINITY; int previ = -1;
    int cI[KTOP];
#pragma unroll
    for (int k = 0; k < KTOP; ++k) {
        bool adm0 = (v0 < prevv) || (v0 == prevv && i0 > previ);
        bool adm1 = (v1 < prevv) || (v1 == prevv && i1 > previ);
        float bv = adm0 ? v0 : -INFINITY;
        int   bi = adm0 ? i0 : 0x7fffffff;
        if (adm1 && (v1 > bv || (v1 == bv && i1 < bi))) { bv = v1; bi = i1; }
#pragma unroll
        for (int off = 1; off < 64; off <<= 1) {
            float ov = __shfl_xor(bv, off, 64);
            int   oi = __shfl_xor(bi, off, 64);
            if (ov > bv || (ov == bv && oi < bi)) { bv = ov; bi = oi; }
        }
        cI[k] = bi; prevv = bv; previ = bi;
    }

    float4 q = *(const float4*)&Qa[r * DQK + lane * 4];
    float sc[KTOP];
#pragma unroll
    for (int k = 0; k < KTOP; ++k) {
        float4 kk = *(const float4*)&Ka[cI[k] * DQK + lane * 4];
        float p = q.x * kk.x + q.y * kk.y + q.z * kk.z + q.w * kk.w;
#pragma unroll
        for (int off = 32; off; off >>= 1) p += __shfl_xor(p, off, 64);
        sc[k] = p * 0.0625f;   // 1/sqrt(256)
    }
    float m = sc[0];
#pragma unroll
    for (int k = 1; k < KTOP; ++k) m = fmaxf(m, sc[k]);
    float w[KTOP], ssum = 0.f;
#pragma unroll
    for (int k = 0; k < KTOP; ++k) { w[k] = expf(sc[k] - m); ssum += w[k]; }
    float inv = 1.f / ssum;
    float4 o = make_float4(0.f, 0.f, 0.f, 0.f);
#pragma unroll
    for (int k = 0; k < KTOP; ++k) {
        float4 vv = *(const float4*)&Va[cI[k] * DQK + lane * 4];
        float a = w[k] * inv;
        o.x = fmaf(a, vv.x, o.x); o.y = fmaf(a, vv.y, o.y);
        o.z = fmaf(a, vv.z, o.z); o.w = fmaf(a, vv.w, o.w);
    }
    *(float4*)&out[r * DQK + lane * 4] = o;
}

// ================================================================ launch
extern "C" void kernel_launch(void* const* d_in, const int* in_sizes, int n_in,
                              void* d_out, int out_size, void* d_ws, size_t ws_size,
                              hipStream_t stream) {
    const float* user  = (const float*)d_in[0];
    const float* item  = (const float*)d_in[1];
    const int*   nrows = (const int*)d_in[2];
    const int*   ncols = (const int*)d_in[3];
    const float* nvals = (const float*)d_in[4];
    const int*   arows = (const int*)d_in[5];
    const int*   acols = (const int*)d_in[6];
    const float* avals = (const float*)d_in[7];
    const float* Wq = (const float*)d_in[8];  const float* bq = (const float*)d_in[9];
    const float* Wk = (const float*)d_in[10]; const float* bk = (const float*)d_in[11];
    const float* Wv = (const float*)d_in[12]; const float* bv = (const float*)d_in[13];
    float* out = (float*)d_out;
    float* ws  = (float*)d_ws;

    const int NE  = NN * EDIM;             // 393216
    const int NQK = NN * DQK;              // 1572864
    float* ego1 = ws;
    float* ego2 = ws + NE;
    float* Qm   = ws + 2 * NE;
    float* Qa   = ws + 3 * NE;
    float* Ka   = Qa + NQK;
    float* Va   = Ka + NQK;
    float* pval = Va + NQK;
    int*   pidx = (int*)(pval + NN * SPLITS * KTOP);

    // CSR scratch aliased over Qa..Va (dead until qkv_gemm)
    int* csr     = (int*)Qa;
    int* cnt_n   = csr;
    int* cnt_a   = csr + 6144;
    int* start_n = csr + 12288;            // 6145
    int* start_a = csr + 18433;            // 6145
    int* cur_n   = csr + 24578;
    int* cur_a   = csr + 30722;
    int2* cv_n   = (int2*)(csr + 36866);
    int2* cv_a   = cv_n + NNZ;

    // zero histograms (graph-capture-legal memset node)
    hipMemsetAsync(cnt_n, 0, 12288 * sizeof(int), stream);
    hist_kernel<<<(2 * NNZ + TPB - 1) / TPB, TPB, 0, stream>>>(nrows, arows, cnt_n, cnt_a);
    scan_kernel<<<2, 1024, 0, stream>>>(cnt_n, cnt_a, start_n, start_a, cur_n, cur_a);
    scatter_kernel<<<(2 * NNZ + TPB - 1) / TPB, TPB, 0, stream>>>(nrows, ncols, nvals,
                                                                  arows, acols, avals,
                                                                  cur_n, cur_a, cv_n, cv_a);
    spmm_csr_emb_kernel<<<NN / 4, TPB, 0, stream>>>(start_n, cv_n, user, item, ego1);
    spmm_csr_kernel<<<NN / 4, TPB, 0, stream>>>(start_n, cv_n, ego1, ego2);
    qm_mean_kernel<<<NN / 4, TPB, 0, stream>>>(start_a, cv_a, ego2, ego1, user, item, Qm, out);
    qkv_gemm_kernel<<<dim3(NN / 64, DQK / 128, 3), TPB, 0, stream>>>(ego2, Wq, bq, Wk, bk, Wv, bv,
                                                                     Qa, Ka, Va);
    topk_partial_kernel<<<dim3(NN / 64, SPLITS), TPB, 0, stream>>>(Qm, ego2, pval, pidx);
    attn_kernel<<<NN / 4, TPB, 0, stream>>>(Qa, Ka, Va, pval, pidx, out + NE);
}

// Round 6
// 266.641 us; speedup vs baseline: 3.7399x; 1.0413x over previous
//
#include <hip/hip_runtime.h>
#include <math.h>

#define NUSER 2560
#define NITEM 3584
#define NN    6144
#define EDIM  64
#define NNZ   200000
#define DQK   256
#define KTOP  5
#define SPLITS 8
#define TPS    6          // 48 cand tiles / 8 splits
#define TPB   256
#define QKV_BLOCKS 576    // 96 rowtiles x 2 dtiles x 3 matrices
#define TOPK_BLOCKS (96 * SPLITS)

// ================================================================ CSR build
__global__ void hist_kernel(const int* __restrict__ nr, const int* __restrict__ ar,
                            int* __restrict__ cnt_n, int* __restrict__ cnt_a) {
    int g = blockIdx.x * TPB + threadIdx.x;
    if (g < NNZ) atomicAdd(&cnt_n[nr[g]], 1);
    else if (g < 2 * NNZ) atomicAdd(&cnt_a[ar[g - NNZ]], 1);
}

// 1024 threads x 6 elems; wave-shuffle scan (2 barriers total)
__global__ void scan_kernel(const int* __restrict__ cnt_n, const int* __restrict__ cnt_a,
                            int* __restrict__ start_n, int* __restrict__ start_a,
                            int* __restrict__ cur_n, int* __restrict__ cur_a) {
    const int* cnt = blockIdx.x ? cnt_a : cnt_n;
    int* start = blockIdx.x ? start_a : start_n;
    int* cur   = blockIdx.x ? cur_a   : cur_n;
    int t = threadIdx.x;
    int loc[6]; int p = 0;
#pragma unroll
    for (int j = 0; j < 6; ++j) { loc[j] = cnt[t * 6 + j]; p += loc[j]; }
    int lane = t & 63, wid = t >> 6;
    int inc = p;
#pragma unroll
    for (int off = 1; off < 64; off <<= 1) {
        int v = __shfl_up(inc, off, 64);
        if (lane >= off) inc += v;
    }
    __shared__ int wsum[16];
    if (lane == 63) wsum[wid] = inc;
    __syncthreads();
    if (t < 16) {
        int sc = wsum[t];
#pragma unroll
        for (int off = 1; off < 16; off <<= 1) {
            int u = __shfl_up(sc, off, 16);
            if (t >= off) sc += u;
        }
        wsum[t] = sc;
    }
    __syncthreads();
    int ex = inc - p + (wid ? wsum[wid - 1] : 0);
#pragma unroll
    for (int j = 0; j < 6; ++j) { start[t * 6 + j] = ex; cur[t * 6 + j] = ex; ex += loc[j]; }
    if (t == 1023) start[NN] = ex;
}

__global__ void scatter_kernel(const int* __restrict__ nr, const int* __restrict__ nc,
                               const float* __restrict__ nv,
                               const int* __restrict__ ar, const int* __restrict__ ac,
                               const float* __restrict__ av,
                               int* __restrict__ cur_n, int* __restrict__ cur_a,
                               int2* __restrict__ cv_n, int2* __restrict__ cv_a) {
    int g = blockIdx.x * TPB + threadIdx.x;
    if (g < NNZ) {
        int pos = atomicAdd(&cur_n[nr[g]], 1);
        cv_n[pos] = make_int2(nc[g], __float_as_int(nv[g]));
    } else if (g < 2 * NNZ) {
        int h = g - NNZ;
        int pos = atomicAdd(&cur_a[ar[h]], 1);
        cv_a[pos] = make_int2(ac[h], __float_as_int(av[h]));
    }
}

// ================================================================ CSR SpMM, wave-per-row, x8 unroll
__global__ __launch_bounds__(TPB) void spmm_csr_emb_kernel(
        const int* __restrict__ start, const int2* __restrict__ cv,
        const float* __restrict__ user, const float* __restrict__ item,
        float* __restrict__ dst) {
    int r = blockIdx.x * 4 + (threadIdx.x >> 6);
    int lane = threadIdx.x & 63;
    int s = start[r], e = start[r + 1];
    float a[8];
#pragma unroll
    for (int u = 0; u < 8; ++u) a[u] = 0.f;
    int j = s, n8 = s + ((e - s) & ~7);
    for (; j < n8; j += 8) {
        int2 c[8];
#pragma unroll
        for (int u = 0; u < 8; ++u) c[u] = cv[j + u];
#pragma unroll
        for (int u = 0; u < 8; ++u) {
            float x = (c[u].x < NUSER) ? user[c[u].x * EDIM + lane]
                                       : item[(c[u].x - NUSER) * EDIM + lane];
            a[u] = fmaf(__int_as_float(c[u].y), x, a[u]);
        }
    }
    for (; j < e; ++j) {
        int2 c = cv[j];
        float x = (c.x < NUSER) ? user[c.x * EDIM + lane] : item[(c.x - NUSER) * EDIM + lane];
        a[0] = fmaf(__int_as_float(c.y), x, a[0]);
    }
    dst[r * EDIM + lane] = ((a[0] + a[1]) + (a[2] + a[3])) + ((a[4] + a[5]) + (a[6] + a[7]));
}

__global__ __launch_bounds__(TPB) void spmm_csr_kernel(
        const int* __restrict__ start, const int2* __restrict__ cv,
        const float* __restrict__ src, float* __restrict__ dst) {
    int r = blockIdx.x * 4 + (threadIdx.x >> 6);
    int lane = threadIdx.x & 63;
    int s = start[r], e = start[r + 1];
    float a[8];
#pragma unroll
    for (int u = 0; u < 8; ++u) a[u] = 0.f;
    int j = s, n8 = s + ((e - s) & ~7);
    for (; j < n8; j += 8) {
        int2 c[8];
#pragma unroll
        for (int u = 0; u < 8; ++u) c[u] = cv[j + u];
#pragma unroll
        for (int u = 0; u < 8; ++u)
            a[u] = fmaf(__int_as_float(c[u].y), src[c[u].x * EDIM + lane], a[u]);
    }
    for (; j < e; ++j) {
        int2 c = cv[j];
        a[0] = fmaf(__int_as_float(c.y), src[c.x * EDIM + lane], a[0]);
    }
    dst[r * EDIM + lane] = ((a[0] + a[1]) + (a[2] + a[3])) + ((a[4] + a[5]) + (a[6] + a[7]));
}

// Qm = ego2 + 0.5*(A@ego2) ; outmean = 0.5*(ego0+ego1)
__global__ __launch_bounds__(TPB) void qm_mean_kernel(
        const int* __restrict__ start, const int2* __restrict__ cv,
        const float* __restrict__ ego2, const float* __restrict__ ego1,
        const float* __restrict__ user, const float* __restrict__ item,
        float* __restrict__ Qm, float* __restrict__ outmean) {
    int r = blockIdx.x * 4 + (threadIdx.x >> 6);
    int lane = threadIdx.x & 63;
    int s = start[r], e = start[r + 1];
    float a[8];
#pragma unroll
    for (int u = 0; u < 8; ++u) a[u] = 0.f;
    int j = s, n8 = s + ((e - s) & ~7);
    for (; j < n8; j += 8) {
        int2 c[8];
#pragma unroll
        for (int u = 0; u < 8; ++u) c[u] = cv[j + u];
#pragma unroll
        for (int u = 0; u < 8; ++u)
            a[u] = fmaf(__int_as_float(c[u].y), ego2[c[u].x * EDIM + lane], a[u]);
    }
    for (; j < e; ++j) {
        int2 c = cv[j];
        a[0] = fmaf(__int_as_float(c.y), ego2[c.x * EDIM + lane], a[0]);
    }
    float acc = ((a[0] + a[1]) + (a[2] + a[3])) + ((a[4] + a[5]) + (a[6] + a[7]));
    int o = r * EDIM + lane;
    Qm[o] = ego2[o] + 0.5f * acc;
    float e0v = (r < NUSER) ? user[o] : item[o - NUSER * EDIM];
    outmean[o] = 0.5f * (e0v + ego1[o]);
}

// ================================================================ fused QKV-GEMM + sim-top5 (independent work)
__device__ __forceinline__ void ins5(float v, int ci, float tv[KTOP], int ti[KTOP]) {
    if (v > tv[4]) {
#pragma unroll
        for (int k = 4; k >= 1; --k) {
            bool sh = v > tv[k];
            bool ph = v > tv[k - 1];
            float nv = ph ? tv[k - 1] : v;
            int   ni = ph ? ti[k - 1] : ci;
            if (sh) { tv[k] = nv; ti[k] = ni; }
        }
        if (v > tv[0]) { tv[0] = v; ti[0] = ci; }
    }
}

__global__ __launch_bounds__(TPB, 3) void qkv_topk_kernel(
        const float* __restrict__ ego2,
        const float* __restrict__ Wq, const float* __restrict__ bq,
        const float* __restrict__ Wk, const float* __restrict__ bk,
        const float* __restrict__ Wv, const float* __restrict__ bv,
        float* __restrict__ Qa, float* __restrict__ Ka, float* __restrict__ Va,
        const float* __restrict__ Qm,
        float* __restrict__ pval, int* __restrict__ pidx) {
    __shared__ __align__(16) float smem[12288];   // 48 KB both paths
    int t = threadIdx.x, tx = t & 15, ty = t >> 4;

    if (blockIdx.x < QKV_BLOCKS) {
        // ---------------- QKV GEMM path (validated structure) ----------------
        int id = blockIdx.x;
        int bz = id / 192, rem = id % 192, by = rem / 96, bx = rem % 96;
        const float* W; const float* b; float* out;
        if (bz == 0)      { W = Wq; b = bq; out = Qa; }
        else if (bz == 1) { W = Wk; b = bk; out = Ka; }
        else              { W = Wv; b = bv; out = Va; }
        float* As = smem;
        float* Bs = smem + 4096;
        int r0 = bx * 64, d0 = by * 128;
        {
            int r = t & 63, eb = (t >> 6) * 16;
#pragma unroll
            for (int rep = 0; rep < 4; ++rep) {
                int e0 = eb + rep * 4;
                float4 v = *(const float4*)&ego2[(r0 + r) * EDIM + e0];
                As[(e0 + 0) * 64 + r] = v.x; As[(e0 + 1) * 64 + r] = v.y;
                As[(e0 + 2) * 64 + r] = v.z; As[(e0 + 3) * 64 + r] = v.w;
            }
        }
        {
            int d = t & 127, eb = (t >> 7) * 32;
#pragma unroll
            for (int rep = 0; rep < 8; ++rep) {
                int e0 = eb + rep * 4;
                float4 v = *(const float4*)&W[(d0 + d) * EDIM + e0];
                Bs[(e0 + 0) * 128 + d] = v.x; Bs[(e0 + 1) * 128 + d] = v.y;
                Bs[(e0 + 2) * 128 + d] = v.z; Bs[(e0 + 3) * 128 + d] = v.w;
            }
        }
        __syncthreads();
        float acc[4][8];
#pragma unroll
        for (int i = 0; i < 4; ++i)
#pragma unroll
            for (int j = 0; j < 8; ++j) acc[i][j] = 0.f;
#pragma unroll 4
        for (int e = 0; e < 64; ++e) {
            float4 a  = *(const float4*)&As[e * 64 + ty * 4];
            float4 b0 = *(const float4*)&Bs[e * 128 + tx * 4];
            float4 b1 = *(const float4*)&Bs[e * 128 + 64 + tx * 4];
            float ar[4] = {a.x, a.y, a.z, a.w};
#pragma unroll
            for (int i = 0; i < 4; ++i) {
                acc[i][0] = fmaf(ar[i], b0.x, acc[i][0]);
                acc[i][1] = fmaf(ar[i], b0.y, acc[i][1]);
                acc[i][2] = fmaf(ar[i], b0.z, acc[i][2]);
                acc[i][3] = fmaf(ar[i], b0.w, acc[i][3]);
                acc[i][4] = fmaf(ar[i], b1.x, acc[i][4]);
                acc[i][5] = fmaf(ar[i], b1.y, acc[i][5]);
                acc[i][6] = fmaf(ar[i], b1.z, acc[i][6]);
                acc[i][7] = fmaf(ar[i], b1.w, acc[i][7]);
            }
        }
        float4 bias0 = *(const float4*)&b[d0 + tx * 4];
        float4 bias1 = *(const float4*)&b[d0 + 64 + tx * 4];
#pragma unroll
        for (int i = 0; i < 4; ++i) {
            int r = r0 + ty * 4 + i;
            float4 o0 = make_float4(acc[i][0] + bias0.x, acc[i][1] + bias0.y,
                                    acc[i][2] + bias0.z, acc[i][3] + bias0.w);
            float4 o1 = make_float4(acc[i][4] + bias1.x, acc[i][5] + bias1.y,
                                    acc[i][6] + bias1.z, acc[i][7] + bias1.w);
            *(float4*)&out[r * DQK + d0 + tx * 4] = o0;
            *(float4*)&out[r * DQK + d0 + 64 + tx * 4] = o1;
        }
        return;
    }

    // ---------------- topk path: 64 rows x (TPS x 128 cands), register-prefetch pipeline ----------------
    int id = blockIdx.x - QKV_BLOCKS;
    int rb = id % 96, s = id / 96;
    int r0 = rb * 64;
    float* Qs = smem;           // [e][r] stride 64
    float* Ps = smem + 4096;    // [e][c] stride 128

    { // stage Q transposed (once per block)
        int r = t & 63, eb = (t >> 6) * 16;
#pragma unroll
        for (int rep = 0; rep < 4; ++rep) {
            int e0 = eb + rep * 4;
            float4 v = *(const float4*)&Qm[(r0 + r) * EDIM + e0];
            Qs[(e0 + 0) * 64 + r] = v.x; Qs[(e0 + 1) * 64 + r] = v.y;
            Qs[(e0 + 2) * 64 + r] = v.z; Qs[(e0 + 3) * 64 + r] = v.w;
        }
    }

    int pc = t & 127, pe = (t >> 7) * 32;     // this thread's P-staging coords
    float4 pf[8];
    { // prefetch tile 0 into registers
        int c0 = (s * TPS) * 128;
#pragma unroll
        for (int rep = 0; rep < 8; ++rep)
            pf[rep] = *(const float4*)&ego2[(c0 + pc) * EDIM + pe + rep * 4];
    }

    float t5v[4][KTOP]; int t5i[4][KTOP];
#pragma unroll
    for (int i = 0; i < 4; ++i)
#pragma unroll
        for (int k = 0; k < KTOP; ++k) { t5v[i][k] = -INFINITY; t5i[i][k] = 0x7fffffff; }

    for (int tile = 0; tile < TPS; ++tile) {
        int c0 = (s * TPS + tile) * 128;
        __syncthreads();            // Ps consumed by previous compute (tile0: Qs ready)
        { // write prefetched tile to LDS (transposed)
#pragma unroll
            for (int rep = 0; rep < 8; ++rep) {
                int e0 = pe + rep * 4;
                Ps[(e0 + 0) * 128 + pc] = pf[rep].x; Ps[(e0 + 1) * 128 + pc] = pf[rep].y;
                Ps[(e0 + 2) * 128 + pc] = pf[rep].z; Ps[(e0 + 3) * 128 + pc] = pf[rep].w;
            }
        }
        if (tile + 1 < TPS) { // prefetch next tile (lands during this tile's compute)
            int c1 = c0 + 128;
#pragma unroll
            for (int rep = 0; rep < 8; ++rep)
                pf[rep] = *(const float4*)&ego2[(c1 + pc) * EDIM + pe + rep * 4];
        }
        __syncthreads();

        float acc[4][8];
#pragma unroll
        for (int i = 0; i < 4; ++i)
#pragma unroll
            for (int j = 0; j < 8; ++j) acc[i][j] = 0.f;

#pragma unroll 4
        for (int e = 0; e < 64; ++e) {
            float4 a  = *(const float4*)&Qs[e * 64 + ty * 4];
            float4 b0 = *(const float4*)&Ps[e * 128 + tx * 4];
            float4 b1 = *(const float4*)&Ps[e * 128 + 64 + tx * 4];
            float ar[4] = {a.x, a.y, a.z, a.w};
#pragma unroll
            for (int i = 0; i < 4; ++i) {
                acc[i][0] = fmaf(ar[i], b0.x, acc[i][0]);
                acc[i][1] = fmaf(ar[i], b0.y, acc[i][1]);
                acc[i][2] = fmaf(ar[i], b0.z, acc[i][2]);
                acc[i][3] = fmaf(ar[i], b0.w, acc[i][3]);
                acc[i][4] = fmaf(ar[i], b1.x, acc[i][4]);
                acc[i][5] = fmaf(ar[i], b1.y, acc[i][5]);
                acc[i][6] = fmaf(ar[i], b1.z, acc[i][6]);
                acc[i][7] = fmaf(ar[i], b1.w, acc[i][7]);
            }
        }

        // per-thread candidate order increasing in ci -> first-seen keeps lowest index on ties
#pragma unroll
        for (int i = 0; i < 4; ++i)
#pragma unroll
            for (int j = 0; j < 8; ++j) {
                int ci = c0 + (j >> 2) * 64 + tx * 4 + (j & 3);
                ins5(acc[i][j], ci, t5v[i], t5i[i]);
            }
    }

    // wave-shuffle merge of 16 per-thread lists per row (no LDS, no barriers)
#pragma unroll
    for (int i = 0; i < 4; ++i) {
        int row = r0 + ty * 4 + i;
        int ptr = 0;
        for (int k = 0; k < KTOP; ++k) {
            float cvv; int cii;
            cvv = (ptr == 0) ? t5v[i][0] : (ptr == 1) ? t5v[i][1] : (ptr == 2) ? t5v[i][2]
                : (ptr == 3) ? t5v[i][3] : (ptr == 4) ? t5v[i][4] : -INFINITY;
            cii = (ptr == 0) ? t5i[i][0] : (ptr == 1) ? t5i[i][1] : (ptr == 2) ? t5i[i][2]
                : (ptr == 3) ? t5i[i][3] : (ptr == 4) ? t5i[i][4] : 0x7fffffff;
            float bv = cvv; int bi = cii;
#pragma unroll
            for (int off = 1; off < 16; off <<= 1) {
                float ov = __shfl_xor(bv, off, 64);
                int   oi = __shfl_xor(bi, off, 64);
                if (ov > bv || (ov == bv && oi < bi)) { bv = ov; bi = oi; }
            }
            if (bv == cvv && bi == cii) ptr++;
            if (tx == 0) {
                int o = (row * SPLITS + s) * KTOP + k;
                pval[o] = bv; pidx[o] = bi;
            }
        }
    }
}

// ================================================================ fused final-merge + attention
__global__ __launch_bounds__(TPB) void attn_kernel(
        const float* __restrict__ Qa, const float* __restrict__ Ka, const float* __restrict__ Va,
        const float* __restrict__ pval, const int* __restrict__ pidx, float* __restrict__ out) {
    int wv = threadIdx.x >> 6, lane = threadIdx.x & 63;
    int r = blockIdx.x * 4 + wv;
    const float* pv = pval + r * SPLITS * KTOP;    // 40 entries
    const int*   pi = pidx + r * SPLITS * KTOP;
    float v0 = (lane < SPLITS * KTOP) ? pv[lane] : -INFINITY;
    int   i0 = (lane < SPLITS * KTOP) ? pi[lane] : 0x7fffffff;

    float prevv = INFINITY; int previ = -1;
    int cI[KTOP];
#pragma unroll
    for (int k = 0; k < KTOP; ++k) {
        bool adm = (v0 < prevv) || (v0 == prevv && i0 > previ);
        float bv = adm ? v0 : -INFINITY;
        int   bi = adm ? i0 : 0x7fffffff;
#pragma unroll
        for (int off = 1; off < 64; off <<= 1) {
            float ov = __shfl_xor(bv, off, 64);
            int   oi = __shfl_xor(bi, off, 64);
            if (ov > bv || (ov == bv && oi < bi)) { bv = ov; bi = oi; }
        }
        cI[k] = bi; prevv = bv; previ = bi;
    }

    float4 q = *(const float4*)&Qa[r * DQK + lane * 4];
    float sc[KTOP];
#pragma unroll
    for (int k = 0; k < KTOP; ++k) {
        float4 kk = *(const float4*)&Ka[cI[k] * DQK + lane * 4];
        float p = q.x * kk.x + q.y * kk.y + q.z * kk.z + q.w * kk.w;
#pragma unroll
        for (int off = 32; off; off >>= 1) p += __shfl_xor(p, off, 64);
        sc[k] = p * 0.0625f;   // 1/sqrt(256)
    }
    float m = sc[0];
#pragma unroll
    for (int k = 1; k < KTOP; ++k) m = fmaxf(m, sc[k]);
    float w[KTOP], ssum = 0.f;
#pragma unroll
    for (int k = 0; k < KTOP; ++k) { w[k] = expf(sc[k] - m); ssum += w[k]; }
    float inv = 1.f / ssum;
    float4 o = make_float4(0.f, 0.f, 0.f, 0.f);
#pragma unroll
    for (int k = 0; k < KTOP; ++k) {
        float4 vv = *(const float4*)&Va[cI[k] * DQK + lane * 4];
        float a = w[k] * inv;
        o.x = fmaf(a, vv.x, o.x); o.y = fmaf(a, vv.y, o.y);
        o.z = fmaf(a, vv.z, o.z); o.w = fmaf(a, vv.w, o.w);
    }
    *(float4*)&out[r * DQK + lane * 4] = o;
}

// ================================================================ launch
extern "C" void kernel_launch(void* const* d_in, const int* in_sizes, int n_in,
                              void* d_out, int out_size, void* d_ws, size_t ws_size,
                              hipStream_t stream) {
    const float* user  = (const float*)d_in[0];
    const float* item  = (const float*)d_in[1];
    const int*   nrows = (const int*)d_in[2];
    const int*   ncols = (const int*)d_in[3];
    const float* nvals = (const float*)d_in[4];
    const int*   arows = (const int*)d_in[5];
    const int*   acols = (const int*)d_in[6];
    const float* avals = (const float*)d_in[7];
    const float* Wq = (const float*)d_in[8];  const float* bq = (const float*)d_in[9];
    const float* Wk = (const float*)d_in[10]; const float* bk = (const float*)d_in[11];
    const float* Wv = (const float*)d_in[12]; const float* bv = (const float*)d_in[13];
    float* out = (float*)d_out;
    float* ws  = (float*)d_ws;

    const int NE  = NN * EDIM;             // 393216
    const int NQK = NN * DQK;              // 1572864
    float* ego1 = ws;
    float* ego2 = ws + NE;
    float* Qm   = ws + 2 * NE;
    float* Qa   = ws + 3 * NE;
    float* Ka   = Qa + NQK;
    float* Va   = Ka + NQK;
    float* pval = Va + NQK;
    int*   pidx = (int*)(pval + NN * SPLITS * KTOP);

    // CSR scratch aliased over Qa..Va (dead until qkv_topk)
    int* csr     = (int*)Qa;
    int* cnt_n   = csr;
    int* cnt_a   = csr + 6144;
    int* start_n = csr + 12288;            // 6145
    int* start_a = csr + 18433;            // 6145
    int* cur_n   = csr + 24578;
    int* cur_a   = csr + 30722;
    int2* cv_n   = (int2*)(csr + 36866);
    int2* cv_a   = cv_n + NNZ;

    hipMemsetAsync(cnt_n, 0, 12288 * sizeof(int), stream);
    hist_kernel<<<(2 * NNZ + TPB - 1) / TPB, TPB, 0, stream>>>(nrows, arows, cnt_n, cnt_a);
    scan_kernel<<<2, 1024, 0, stream>>>(cnt_n, cnt_a, start_n, start_a, cur_n, cur_a);
    scatter_kernel<<<(2 * NNZ + TPB - 1) / TPB, TPB, 0, stream>>>(nrows, ncols, nvals,
                                                                  arows, acols, avals,
                                                                  cur_n, cur_a, cv_n, cv_a);
    spmm_csr_emb_kernel<<<NN / 4, TPB, 0, stream>>>(start_n, cv_n, user, item, ego1);
    spmm_csr_kernel<<<NN / 4, TPB, 0, stream>>>(start_n, cv_n, ego1, ego2);
    qm_mean_kernel<<<NN / 4, TPB, 0, stream>>>(start_a, cv_a, ego2, ego1, user, item, Qm, out);
    qkv_topk_kernel<<<QKV_BLOCKS + TOPK_BLOCKS, TPB, 0, stream>>>(
        ego2, Wq, bq, Wk, bk, Wv, bv, Qa, Ka, Va, Qm, pval, pidx);
    attn_kernel<<<NN / 4, TPB, 0, stream>>>(Qa, Ka, Va, pval, pidx, out + NE);
}

// Round 7
// 225.301 us; speedup vs baseline: 4.4262x; 1.1835x over previous
//
#include <hip/hip_runtime.h>
#include <math.h>

#define NUSER 2560
#define NITEM 3584
#define NN    6144
#define EDIM  64
#define NNZ   200000
#define DQK   256
#define KTOP  5
#define SPLITS 8
#define TPS    6          // 48 cand tiles / 8 splits
#define CK     8          // coarse candidates kept per (row, split); 8*8=64 rescored
#define TPB   256
#define QKV_BLOCKS 576    // 96 rowtiles x 2 dtiles x 3 matrices
#define TOPK_BLOCKS (96 * SPLITS)

typedef __attribute__((ext_vector_type(8))) short bf16x8;
typedef __attribute__((ext_vector_type(4))) float f32x4;

__device__ __forceinline__ unsigned short f2bf(float f) {
    unsigned int b = __float_as_uint(f);
    unsigned int r = (b + 0x7FFFu + ((b >> 16) & 1u)) >> 16;
    return (unsigned short)r;
}

// ================================================================ CSR build
__global__ void hist_kernel(const int* __restrict__ nr, const int* __restrict__ ar,
                            int* __restrict__ cnt_n, int* __restrict__ cnt_a) {
    int g = blockIdx.x * TPB + threadIdx.x;
    if (g < NNZ) atomicAdd(&cnt_n[nr[g]], 1);
    else if (g < 2 * NNZ) atomicAdd(&cnt_a[ar[g - NNZ]], 1);
}

__global__ void scan_kernel(const int* __restrict__ cnt_n, const int* __restrict__ cnt_a,
                            int* __restrict__ start_n, int* __restrict__ start_a,
                            int* __restrict__ cur_n, int* __restrict__ cur_a) {
    const int* cnt = blockIdx.x ? cnt_a : cnt_n;
    int* start = blockIdx.x ? start_a : start_n;
    int* cur   = blockIdx.x ? cur_a   : cur_n;
    int t = threadIdx.x;
    int loc[6]; int p = 0;
#pragma unroll
    for (int j = 0; j < 6; ++j) { loc[j] = cnt[t * 6 + j]; p += loc[j]; }
    int lane = t & 63, wid = t >> 6;
    int inc = p;
#pragma unroll
    for (int off = 1; off < 64; off <<= 1) {
        int v = __shfl_up(inc, off, 64);
        if (lane >= off) inc += v;
    }
    __shared__ int wsum[16];
    if (lane == 63) wsum[wid] = inc;
    __syncthreads();
    if (t < 16) {
        int sc = wsum[t];
#pragma unroll
        for (int off = 1; off < 16; off <<= 1) {
            int u = __shfl_up(sc, off, 16);
            if (t >= off) sc += u;
        }
        wsum[t] = sc;
    }
    __syncthreads();
    int ex = inc - p + (wid ? wsum[wid - 1] : 0);
#pragma unroll
    for (int j = 0; j < 6; ++j) { start[t * 6 + j] = ex; cur[t * 6 + j] = ex; ex += loc[j]; }
    if (t == 1023) start[NN] = ex;
}

__global__ void scatter_kernel(const int* __restrict__ nr, const int* __restrict__ nc,
                               const float* __restrict__ nv,
                               const int* __restrict__ ar, const int* __restrict__ ac,
                               const float* __restrict__ av,
                               int* __restrict__ cur_n, int* __restrict__ cur_a,
                               int2* __restrict__ cv_n, int2* __restrict__ cv_a) {
    int g = blockIdx.x * TPB + threadIdx.x;
    if (g < NNZ) {
        int pos = atomicAdd(&cur_n[nr[g]], 1);
        cv_n[pos] = make_int2(nc[g], __float_as_int(nv[g]));
    } else if (g < 2 * NNZ) {
        int h = g - NNZ;
        int pos = atomicAdd(&cur_a[ar[h]], 1);
        cv_a[pos] = make_int2(ac[h], __float_as_int(av[h]));
    }
}

// ================================================================ CSR SpMM, wave-per-row, x8 unroll
__global__ __launch_bounds__(TPB) void spmm_csr_emb_kernel(
        const int* __restrict__ start, const int2* __restrict__ cv,
        const float* __restrict__ user, const float* __restrict__ item,
        float* __restrict__ dst) {
    int r = blockIdx.x * 4 + (threadIdx.x >> 6);
    int lane = threadIdx.x & 63;
    int s = start[r], e = start[r + 1];
    float a[8];
#pragma unroll
    for (int u = 0; u < 8; ++u) a[u] = 0.f;
    int j = s, n8 = s + ((e - s) & ~7);
    for (; j < n8; j += 8) {
        int2 c[8];
#pragma unroll
        for (int u = 0; u < 8; ++u) c[u] = cv[j + u];
#pragma unroll
        for (int u = 0; u < 8; ++u) {
            float x = (c[u].x < NUSER) ? user[c[u].x * EDIM + lane]
                                       : item[(c[u].x - NUSER) * EDIM + lane];
            a[u] = fmaf(__int_as_float(c[u].y), x, a[u]);
        }
    }
    for (; j < e; ++j) {
        int2 c = cv[j];
        float x = (c.x < NUSER) ? user[c.x * EDIM + lane] : item[(c.x - NUSER) * EDIM + lane];
        a[0] = fmaf(__int_as_float(c.y), x, a[0]);
    }
    dst[r * EDIM + lane] = ((a[0] + a[1]) + (a[2] + a[3])) + ((a[4] + a[5]) + (a[6] + a[7]));
}

__global__ __launch_bounds__(TPB) void spmm_csr_kernel(
        const int* __restrict__ start, const int2* __restrict__ cv,
        const float* __restrict__ src, float* __restrict__ dst) {
    int r = blockIdx.x * 4 + (threadIdx.x >> 6);
    int lane = threadIdx.x & 63;
    int s = start[r], e = start[r + 1];
    float a[8];
#pragma unroll
    for (int u = 0; u < 8; ++u) a[u] = 0.f;
    int j = s, n8 = s + ((e - s) & ~7);
    for (; j < n8; j += 8) {
        int2 c[8];
#pragma unroll
        for (int u = 0; u < 8; ++u) c[u] = cv[j + u];
#pragma unroll
        for (int u = 0; u < 8; ++u)
            a[u] = fmaf(__int_as_float(c[u].y), src[c[u].x * EDIM + lane], a[u]);
    }
    for (; j < e; ++j) {
        int2 c = cv[j];
        a[0] = fmaf(__int_as_float(c.y), src[c.x * EDIM + lane], a[0]);
    }
    dst[r * EDIM + lane] = ((a[0] + a[1]) + (a[2] + a[3])) + ((a[4] + a[5]) + (a[6] + a[7]));
}

// Qm = ego2 + 0.5*(A@ego2) ; outmean = 0.5*(ego0+ego1) ; also emit bf16 copies of Qm, ego2
__global__ __launch_bounds__(TPB) void qm_mean_kernel(
        const int* __restrict__ start, const int2* __restrict__ cv,
        const float* __restrict__ ego2, const float* __restrict__ ego1,
        const float* __restrict__ user, const float* __restrict__ item,
        float* __restrict__ Qm, float* __restrict__ outmean,
        unsigned short* __restrict__ Qmh, unsigned short* __restrict__ E2h) {
    int r = blockIdx.x * 4 + (threadIdx.x >> 6);
    int lane = threadIdx.x & 63;
    int s = start[r], e = start[r + 1];
    float a[8];
#pragma unroll
    for (int u = 0; u < 8; ++u) a[u] = 0.f;
    int j = s, n8 = s + ((e - s) & ~7);
    for (; j < n8; j += 8) {
        int2 c[8];
#pragma unroll
        for (int u = 0; u < 8; ++u) c[u] = cv[j + u];
#pragma unroll
        for (int u = 0; u < 8; ++u)
            a[u] = fmaf(__int_as_float(c[u].y), ego2[c[u].x * EDIM + lane], a[u]);
    }
    for (; j < e; ++j) {
        int2 c = cv[j];
        a[0] = fmaf(__int_as_float(c.y), ego2[c.x * EDIM + lane], a[0]);
    }
    float acc = ((a[0] + a[1]) + (a[2] + a[3])) + ((a[4] + a[5]) + (a[6] + a[7]));
    int o = r * EDIM + lane;
    float e2 = ego2[o];
    float qm = e2 + 0.5f * acc;
    Qm[o] = qm;
    Qmh[o] = f2bf(qm);
    E2h[o] = f2bf(e2);
    float e0v = (r < NUSER) ? user[o] : item[o - NUSER * EDIM];
    outmean[o] = 0.5f * (e0v + ego1[o]);
}

// ================================================================ fused QKV-GEMM + MFMA coarse top-8
__device__ __forceinline__ void ins3(float v, int ci, float tv[3], int ti[3]) {
    if (v > tv[2]) {
        bool p1 = v > tv[1], p0 = v > tv[0];
        tv[2] = p1 ? tv[1] : v;  ti[2] = p1 ? ti[1] : ci;
        if (p1) { tv[1] = p0 ? tv[0] : v; ti[1] = p0 ? ti[0] : ci; }
        if (p0) { tv[0] = v; ti[0] = ci; }
    }
}

__global__ __launch_bounds__(TPB, 3) void qkv_topk_kernel(
        const float* __restrict__ ego2,
        const float* __restrict__ Wq, const float* __restrict__ bq,
        const float* __restrict__ Wk, const float* __restrict__ bk,
        const float* __restrict__ Wv, const float* __restrict__ bv,
        float* __restrict__ Qa, float* __restrict__ Ka, float* __restrict__ Va,
        const unsigned short* __restrict__ Qmh, const unsigned short* __restrict__ E2h,
        float* __restrict__ pval, int* __restrict__ pidx) {
    __shared__ __align__(16) float smem[12288];   // 48 KB
    int t = threadIdx.x;

    if (blockIdx.x < QKV_BLOCKS) {
        // ---------------- QKV GEMM path (validated, fp32) ----------------
        int tx = t & 15, ty = t >> 4;
        int id = blockIdx.x;
        int bz = id / 192, rem = id % 192, by = rem / 96, bx = rem % 96;
        const float* W; const float* b; float* out;
        if (bz == 0)      { W = Wq; b = bq; out = Qa; }
        else if (bz == 1) { W = Wk; b = bk; out = Ka; }
        else              { W = Wv; b = bv; out = Va; }
        float* As = smem;
        float* Bs = smem + 4096;
        int r0 = bx * 64, d0 = by * 128;
        {
            int r = t & 63, eb = (t >> 6) * 16;
#pragma unroll
            for (int rep = 0; rep < 4; ++rep) {
                int e0 = eb + rep * 4;
                float4 v = *(const float4*)&ego2[(r0 + r) * EDIM + e0];
                As[(e0 + 0) * 64 + r] = v.x; As[(e0 + 1) * 64 + r] = v.y;
                As[(e0 + 2) * 64 + r] = v.z; As[(e0 + 3) * 64 + r] = v.w;
            }
        }
        {
            int d = t & 127, eb = (t >> 7) * 32;
#pragma unroll
            for (int rep = 0; rep < 8; ++rep) {
                int e0 = eb + rep * 4;
                float4 v = *(const float4*)&W[(d0 + d) * EDIM + e0];
                Bs[(e0 + 0) * 128 + d] = v.x; Bs[(e0 + 1) * 128 + d] = v.y;
                Bs[(e0 + 2) * 128 + d] = v.z; Bs[(e0 + 3) * 128 + d] = v.w;
            }
        }
        __syncthreads();
        float acc[4][8];
#pragma unroll
        for (int i = 0; i < 4; ++i)
#pragma unroll
            for (int j = 0; j < 8; ++j) acc[i][j] = 0.f;
#pragma unroll 4
        for (int e = 0; e < 64; ++e) {
            float4 a  = *(const float4*)&As[e * 64 + ty * 4];
            float4 b0 = *(const float4*)&Bs[e * 128 + tx * 4];
            float4 b1 = *(const float4*)&Bs[e * 128 + 64 + tx * 4];
            float ar[4] = {a.x, a.y, a.z, a.w};
#pragma unroll
            for (int i = 0; i < 4; ++i) {
                acc[i][0] = fmaf(ar[i], b0.x, acc[i][0]);
                acc[i][1] = fmaf(ar[i], b0.y, acc[i][1]);
                acc[i][2] = fmaf(ar[i], b0.z, acc[i][2]);
                acc[i][3] = fmaf(ar[i], b0.w, acc[i][3]);
                acc[i][4] = fmaf(ar[i], b1.x, acc[i][4]);
                acc[i][5] = fmaf(ar[i], b1.y, acc[i][5]);
                acc[i][6] = fmaf(ar[i], b1.z, acc[i][6]);
                acc[i][7] = fmaf(ar[i], b1.w, acc[i][7]);
            }
        }
        float4 bias0 = *(const float4*)&b[d0 + tx * 4];
        float4 bias1 = *(const float4*)&b[d0 + 64 + tx * 4];
#pragma unroll
        for (int i = 0; i < 4; ++i) {
            int r = r0 + ty * 4 + i;
            float4 o0 = make_float4(acc[i][0] + bias0.x, acc[i][1] + bias0.y,
                                    acc[i][2] + bias0.z, acc[i][3] + bias0.w);
            float4 o1 = make_float4(acc[i][4] + bias1.x, acc[i][5] + bias1.y,
                                    acc[i][6] + bias1.z, acc[i][7] + bias1.w);
            *(float4*)&out[r * DQK + d0 + tx * 4] = o0;
            *(float4*)&out[r * DQK + d0 + 64 + tx * 4] = o1;
        }
        return;
    }

    // ---------------- MFMA coarse top-8 path ----------------
    // block: 64 rows x (TPS x 128 cands). wave w: rows r0+w*16..+15.
    // mfma_f32_16x16x32_bf16: A/B frag = 8 contiguous k at row lane&15, k-half (lane>>4)*8;
    // C: col=lane&15, row=(lane>>4)*4+reg  [m89/m120-verified layouts]
    int id = blockIdx.x - QKV_BLOCKS;
    int rb = id % 96, sp = id / 96;
    int r0 = rb * 64;
    int w = t >> 6, lane = t & 63, lq = lane >> 4, lc = lane & 15;

    short* Ah = (short*)smem;            // [64][64] bf16, row-major, 8 KB
    short* Bh = Ah + 64 * EDIM;          // [128][64] bf16, row-major, 16 KB

    { // stage A (Qm bf16 rows r0..r0+63) once: 512 float4
        const float4* Ag = (const float4*)(Qmh + (size_t)r0 * EDIM);
        float4* AhV = (float4*)Ah;
        AhV[t] = Ag[t];
        AhV[t + 256] = Ag[t + 256];
    }

    float t3v[4][3]; int t3i[4][3];
#pragma unroll
    for (int i = 0; i < 4; ++i)
#pragma unroll
        for (int k = 0; k < 3; ++k) { t3v[i][k] = -INFINITY; t3i[i][k] = 0x7fffffff; }

    bf16x8 af0, af1;
    for (int tile = 0; tile < TPS; ++tile) {
        int c0 = (sp * TPS + tile) * 128;
        __syncthreads();    // previous tile's B consumed (tile0: nothing to wait on for Bh)
        { // stage B tile (ego2 bf16 rows c0..c0+127): 1024 float4
            const float4* Bg = (const float4*)(E2h + (size_t)c0 * EDIM);
            float4* BhV = (float4*)Bh;
            BhV[t]       = Bg[t];
            BhV[t + 256] = Bg[t + 256];
            BhV[t + 512] = Bg[t + 512];
            BhV[t + 768] = Bg[t + 768];
        }
        __syncthreads();
        if (tile == 0) {
            af0 = *(const bf16x8*)&Ah[(w * 16 + lc) * EDIM + lq * 8];
            af1 = *(const bf16x8*)&Ah[(w * 16 + lc) * EDIM + 32 + lq * 8];
        }

#pragma unroll
        for (int ch = 0; ch < 8; ++ch) {
            bf16x8 b0 = *(const bf16x8*)&Bh[(ch * 16 + lc) * EDIM + lq * 8];
            bf16x8 b1 = *(const bf16x8*)&Bh[(ch * 16 + lc) * EDIM + 32 + lq * 8];
            f32x4 acc = {0.f, 0.f, 0.f, 0.f};
            acc = __builtin_amdgcn_mfma_f32_16x16x32_bf16(af0, b0, acc, 0, 0, 0);
            acc = __builtin_amdgcn_mfma_f32_16x16x32_bf16(af1, b1, acc, 0, 0, 0);
            int ci = c0 + ch * 16 + lc;   // cand index (C col = lane&15)
#pragma unroll
            for (int reg = 0; reg < 4; ++reg)
                ins3(acc[reg], ci, t3v[reg], t3i[reg]);
        }
    }

    // merge 16 lanes' top-3 lists per row -> split top-8. Row (lq*4+i) lives in lanes lq*16..+15;
    // shfl_xor with off<16 stays inside the quad. R5-verified ptr-merge pattern.
#pragma unroll
    for (int i = 0; i < 4; ++i) {
        int row = r0 + w * 16 + lq * 4 + i;
        int ptr = 0;
        for (int k = 0; k < CK; ++k) {
            float cvv = (ptr == 0) ? t3v[i][0] : (ptr == 1) ? t3v[i][1]
                      : (ptr == 2) ? t3v[i][2] : -INFINITY;
            int   cii = (ptr == 0) ? t3i[i][0] : (ptr == 1) ? t3i[i][1]
                      : (ptr == 2) ? t3i[i][2] : 0x7fffffff;
            float bv = cvv; int bi = cii;
#pragma unroll
            for (int off = 1; off < 16; off <<= 1) {
                float ov = __shfl_xor(bv, off, 64);
                int   oi = __shfl_xor(bi, off, 64);
                if (ov > bv || (ov == bv && oi < bi)) { bv = ov; bi = oi; }
            }
            if (bv == cvv && bi == cii) ptr++;
            if (lc == 0) {
                int o = (row * SPLITS + sp) * CK + k;
                pval[o] = bv; pidx[o] = bi;
            }
        }
    }
}

// ================================================================ exact rescore + top-5 + attention
__global__ __launch_bounds__(TPB) void attn_kernel(
        const float* __restrict__ Qm, const float* __restrict__ ego2,
        const float* __restrict__ Qa, const float* __restrict__ Ka, const float* __restrict__ Va,
        const int* __restrict__ pidx, float* __restrict__ out) {
    int wv = threadIdx.x >> 6, lane = threadIdx.x & 63;
    int r = blockIdx.x * 4 + wv;
    // 64 coarse candidates (8 splits x 8); rescore exactly in fp32
    int ci0 = pidx[r * (SPLITS * CK) + lane];
    const float4* qm4 = (const float4*)(Qm + (size_t)r * EDIM);
    const float4* e24 = (const float4*)(ego2 + (size_t)ci0 * EDIM);
    float sv = 0.f;
#pragma unroll
    for (int e = 0; e < 16; ++e) {
        float4 a = qm4[e], b = e24[e];
        sv = fmaf(a.x, b.x, sv); sv = fmaf(a.y, b.y, sv);
        sv = fmaf(a.z, b.z, sv); sv = fmaf(a.w, b.w, sv);
    }

    float prevv = INFINITY; int previ = -1;
    int cI[KTOP];
#pragma unroll
    for (int k = 0; k < KTOP; ++k) {
        bool adm = (sv < prevv) || (sv == prevv && ci0 > previ);
        float bv = adm ? sv : -INFINITY;
        int   bi = adm ? ci0 : 0x7fffffff;
#pragma unroll
        for (int off = 1; off < 64; off <<= 1) {
            float ov = __shfl_xor(bv, off, 64);
            int   oi = __shfl_xor(bi, off, 64);
            if (ov > bv || (ov == bv && oi < bi)) { bv = ov; bi = oi; }
        }
        cI[k] = bi; prevv = bv; previ = bi;
    }

    float4 q = *(const float4*)&Qa[r * DQK + lane * 4];
    float sc[KTOP];
#pragma unroll
    for (int k = 0; k < KTOP; ++k) {
        float4 kk = *(const float4*)&Ka[cI[k] * DQK + lane * 4];
        float p = q.x * kk.x + q.y * kk.y + q.z * kk.z + q.w * kk.w;
#pragma unroll
        for (int off = 32; off; off >>= 1) p += __shfl_xor(p, off, 64);
        sc[k] = p * 0.0625f;   // 1/sqrt(256)
    }
    float m = sc[0];
#pragma unroll
    for (int k = 1; k < KTOP; ++k) m = fmaxf(m, sc[k]);
    float wgt[KTOP], ssum = 0.f;
#pragma unroll
    for (int k = 0; k < KTOP; ++k) { wgt[k] = expf(sc[k] - m); ssum += wgt[k]; }
    float inv = 1.f / ssum;
    float4 o = make_float4(0.f, 0.f, 0.f, 0.f);
#pragma unroll
    for (int k = 0; k < KTOP; ++k) {
        float4 vv = *(const float4*)&Va[cI[k] * DQK + lane * 4];
        float a = wgt[k] * inv;
        o.x = fmaf(a, vv.x, o.x); o.y = fmaf(a, vv.y, o.y);
        o.z = fmaf(a, vv.z, o.z); o.w = fmaf(a, vv.w, o.w);
    }
    *(float4*)&out[r * DQK + lane * 4] = o;
}

// ================================================================ launch
extern "C" void kernel_launch(void* const* d_in, const int* in_sizes, int n_in,
                              void* d_out, int out_size, void* d_ws, size_t ws_size,
                              hipStream_t stream) {
    const float* user  = (const float*)d_in[0];
    const float* item  = (const float*)d_in[1];
    const int*   nrows = (const int*)d_in[2];
    const int*   ncols = (const int*)d_in[3];
    const float* nvals = (const float*)d_in[4];
    const int*   arows = (const int*)d_in[5];
    const int*   acols = (const int*)d_in[6];
    const float* avals = (const float*)d_in[7];
    const float* Wq = (const float*)d_in[8];  const float* bq = (const float*)d_in[9];
    const float* Wk = (const float*)d_in[10]; const float* bk = (const float*)d_in[11];
    const float* Wv = (const float*)d_in[12]; const float* bv = (const float*)d_in[13];
    float* out = (float*)d_out;
    float* ws  = (float*)d_ws;

    const int NE  = NN * EDIM;             // 393216
    const int NQK = NN * DQK;              // 1572864
    float* ego1 = ws;
    float* ego2 = ws + NE;
    float* Qm   = ws + 2 * NE;
    float* Qa   = ws + 3 * NE;
    float* Ka   = Qa + NQK;
    float* Va   = Ka + NQK;
    float* pval = Va + NQK;
    int*   pidx = (int*)(pval + NN * SPLITS * CK);
    unsigned short* Qmh = (unsigned short*)(pidx + NN * SPLITS * CK);
    unsigned short* E2h = Qmh + NE;

    // CSR scratch aliased over Qa..Va (dead until qkv_topk)
    int* csr     = (int*)Qa;
    int* cnt_n   = csr;
    int* cnt_a   = csr + 6144;
    int* start_n = csr + 12288;            // 6145
    int* start_a = csr + 18433;            // 6145
    int* cur_n   = csr + 24578;
    int* cur_a   = csr + 30722;
    int2* cv_n   = (int2*)(csr + 36866);
    int2* cv_a   = cv_n + NNZ;

    hipMemsetAsync(cnt_n, 0, 12288 * sizeof(int), stream);
    hist_kernel<<<(2 * NNZ + TPB - 1) / TPB, TPB, 0, stream>>>(nrows, arows, cnt_n, cnt_a);
    scan_kernel<<<2, 1024, 0, stream>>>(cnt_n, cnt_a, start_n, start_a, cur_n, cur_a);
    scatter_kernel<<<(2 * NNZ + TPB - 1) / TPB, TPB, 0, stream>>>(nrows, ncols, nvals,
                                                                  arows, acols, avals,
                                                                  cur_n, cur_a, cv_n, cv_a);
    spmm_csr_emb_kernel<<<NN / 4, TPB, 0, stream>>>(start_n, cv_n, user, item, ego1);
    spmm_csr_kernel<<<NN / 4, TPB, 0, stream>>>(start_n, cv_n, ego1, ego2);
    qm_mean_kernel<<<NN / 4, TPB, 0, stream>>>(start_a, cv_a, ego2, ego1, user, item,
                                               Qm, out, Qmh, E2h);
    qkv_topk_kernel<<<QKV_BLOCKS + TOPK_BLOCKS, TPB, 0, stream>>>(
        ego2, Wq, bq, Wk, bk, Wv, bv, Qa, Ka, Va, Qmh, E2h, pval, pidx);
    attn_kernel<<<NN / 4, TPB, 0, stream>>>(Qm, ego2, Qa, Ka, Va, pidx, out + NE);
}

// Round 8
// 210.066 us; speedup vs baseline: 4.7472x; 1.0725x over previous
//
#include <hip/hip_runtime.h>
#include <math.h>

#define NUSER 2560
#define NITEM 3584
#define NN    6144
#define EDIM  64
#define NNZ   200000
#define DQK   256
#define KTOP  5
#define SPLITS 8
#define TPS    6          // 48 cand tiles / 8 splits
#define CK     8          // coarse candidates kept per (row, split); 8*8=64 rescored
#define ELLW   96         // padded-ELL row capacity (max row nnz ~58 at 200k/6144)
#define TPB   256
#define QKV_BLOCKS 576    // 96 rowtiles x 2 dtiles x 3 matrices
#define TOPK_BLOCKS (96 * SPLITS)
#define BSTR  72          // Bh LDS row stride in shorts (144B -> conflict-free ds_read_b128)

typedef __attribute__((ext_vector_type(8))) short bf16x8;
typedef __attribute__((ext_vector_type(4))) float f32x4;

__device__ __forceinline__ unsigned short f2bf(float f) {
    unsigned int b = __float_as_uint(f);
    unsigned int r = (b + 0x7FFFu + ((b >> 16) & 1u)) >> 16;
    return (unsigned short)r;
}

// ================================================================ padded-ELL build (one pass, both matrices)
__global__ void build_kernel(const int* __restrict__ nr, const int* __restrict__ nc,
                             const float* __restrict__ nv,
                             const int* __restrict__ ar, const int* __restrict__ ac,
                             const float* __restrict__ av,
                             int* __restrict__ cnt_n, int* __restrict__ cnt_a,
                             int2* __restrict__ cv_n, int2* __restrict__ cv_a) {
    int g = blockIdx.x * TPB + threadIdx.x;
    if (g < NNZ) {
        int r = nr[g];
        int slot = atomicAdd(&cnt_n[r], 1);
        cv_n[r * ELLW + slot] = make_int2(nc[g], __float_as_int(nv[g]));
    } else if (g < 2 * NNZ) {
        int h = g - NNZ;
        int r = ar[h];
        int slot = atomicAdd(&cnt_a[r], 1);
        cv_a[r * ELLW + slot] = make_int2(ac[h], __float_as_int(av[h]));
    }
}

// ================================================================ ELL SpMM, wave-per-row, x8 unroll
__global__ __launch_bounds__(TPB) void spmm_ell_emb_kernel(
        const int* __restrict__ cnt, const int2* __restrict__ cv,
        const float* __restrict__ user, const float* __restrict__ item,
        float* __restrict__ dst) {
    int r = blockIdx.x * 4 + (threadIdx.x >> 6);
    int lane = threadIdx.x & 63;
    int s = r * ELLW, e = s + cnt[r];
    float a[8];
#pragma unroll
    for (int u = 0; u < 8; ++u) a[u] = 0.f;
    int j = s, n8 = s + ((e - s) & ~7);
    for (; j < n8; j += 8) {
        int2 c[8];
#pragma unroll
        for (int u = 0; u < 8; ++u) c[u] = cv[j + u];
#pragma unroll
        for (int u = 0; u < 8; ++u) {
            float x = (c[u].x < NUSER) ? user[c[u].x * EDIM + lane]
                                       : item[(c[u].x - NUSER) * EDIM + lane];
            a[u] = fmaf(__int_as_float(c[u].y), x, a[u]);
        }
    }
    for (; j < e; ++j) {
        int2 c = cv[j];
        float x = (c.x < NUSER) ? user[c.x * EDIM + lane] : item[(c.x - NUSER) * EDIM + lane];
        a[0] = fmaf(__int_as_float(c.y), x, a[0]);
    }
    dst[r * EDIM + lane] = ((a[0] + a[1]) + (a[2] + a[3])) + ((a[4] + a[5]) + (a[6] + a[7]));
}

__global__ __launch_bounds__(TPB) void spmm_ell_kernel(
        const int* __restrict__ cnt, const int2* __restrict__ cv,
        const float* __restrict__ src, float* __restrict__ dst) {
    int r = blockIdx.x * 4 + (threadIdx.x >> 6);
    int lane = threadIdx.x & 63;
    int s = r * ELLW, e = s + cnt[r];
    float a[8];
#pragma unroll
    for (int u = 0; u < 8; ++u) a[u] = 0.f;
    int j = s, n8 = s + ((e - s) & ~7);
    for (; j < n8; j += 8) {
        int2 c[8];
#pragma unroll
        for (int u = 0; u < 8; ++u) c[u] = cv[j + u];
#pragma unroll
        for (int u = 0; u < 8; ++u)
            a[u] = fmaf(__int_as_float(c[u].y), src[c[u].x * EDIM + lane], a[u]);
    }
    for (; j < e; ++j) {
        int2 c = cv[j];
        a[0] = fmaf(__int_as_float(c.y), src[c.x * EDIM + lane], a[0]);
    }
    dst[r * EDIM + lane] = ((a[0] + a[1]) + (a[2] + a[3])) + ((a[4] + a[5]) + (a[6] + a[7]));
}

// Qm = ego2 + 0.5*(A@ego2) ; outmean = 0.5*(ego0+ego1) ; also emit bf16 copies of Qm, ego2
__global__ __launch_bounds__(TPB) void qm_mean_kernel(
        const int* __restrict__ cnt, const int2* __restrict__ cv,
        const float* __restrict__ ego2, const float* __restrict__ ego1,
        const float* __restrict__ user, const float* __restrict__ item,
        float* __restrict__ Qm, float* __restrict__ outmean,
        unsigned short* __restrict__ Qmh, unsigned short* __restrict__ E2h) {
    int r = blockIdx.x * 4 + (threadIdx.x >> 6);
    int lane = threadIdx.x & 63;
    int s = r * ELLW, e = s + cnt[r];
    float a[8];
#pragma unroll
    for (int u = 0; u < 8; ++u) a[u] = 0.f;
    int j = s, n8 = s + ((e - s) & ~7);
    for (; j < n8; j += 8) {
        int2 c[8];
#pragma unroll
        for (int u = 0; u < 8; ++u) c[u] = cv[j + u];
#pragma unroll
        for (int u = 0; u < 8; ++u)
            a[u] = fmaf(__int_as_float(c[u].y), ego2[c[u].x * EDIM + lane], a[u]);
    }
    for (; j < e; ++j) {
        int2 c = cv[j];
        a[0] = fmaf(__int_as_float(c.y), ego2[c.x * EDIM + lane], a[0]);
    }
    float acc = ((a[0] + a[1]) + (a[2] + a[3])) + ((a[4] + a[5]) + (a[6] + a[7]));
    int o = r * EDIM + lane;
    float e2 = ego2[o];
    float qm = e2 + 0.5f * acc;
    Qm[o] = qm;
    Qmh[o] = f2bf(qm);
    E2h[o] = f2bf(e2);
    float e0v = (r < NUSER) ? user[o] : item[o - NUSER * EDIM];
    outmean[o] = 0.5f * (e0v + ego1[o]);
}

// ================================================================ fused QKV-GEMM + MFMA coarse top-8
__device__ __forceinline__ void ins3(float v, int ci, float tv[3], int ti[3]) {
    if (v > tv[2]) {
        bool p1 = v > tv[1], p0 = v > tv[0];
        tv[2] = p1 ? tv[1] : v;  ti[2] = p1 ? ti[1] : ci;
        if (p1) { tv[1] = p0 ? tv[0] : v; ti[1] = p0 ? ti[0] : ci; }
        if (p0) { tv[0] = v; ti[0] = ci; }
    }
}

__global__ __launch_bounds__(TPB, 3) void qkv_topk_kernel(
        const float* __restrict__ ego2,
        const float* __restrict__ Wq, const float* __restrict__ bq,
        const float* __restrict__ Wk, const float* __restrict__ bk,
        const float* __restrict__ Wv, const float* __restrict__ bv,
        float* __restrict__ Qa, float* __restrict__ Ka, float* __restrict__ Va,
        const unsigned short* __restrict__ Qmh, const unsigned short* __restrict__ E2h,
        int* __restrict__ pidx) {
    __shared__ __align__(16) float smem[12288];   // 48 KB
    int t = threadIdx.x;

    if (blockIdx.x < QKV_BLOCKS) {
        // ---------------- QKV GEMM path (validated, fp32) ----------------
        int tx = t & 15, ty = t >> 4;
        int id = blockIdx.x;
        int bz = id / 192, rem = id % 192, by = rem / 96, bx = rem % 96;
        const float* W; const float* b; float* out;
        if (bz == 0)      { W = Wq; b = bq; out = Qa; }
        else if (bz == 1) { W = Wk; b = bk; out = Ka; }
        else              { W = Wv; b = bv; out = Va; }
        float* As = smem;
        float* Bs = smem + 4096;
        int r0 = bx * 64, d0 = by * 128;
        {
            int r = t & 63, eb = (t >> 6) * 16;
#pragma unroll
            for (int rep = 0; rep < 4; ++rep) {
                int e0 = eb + rep * 4;
                float4 v = *(const float4*)&ego2[(r0 + r) * EDIM + e0];
                As[(e0 + 0) * 64 + r] = v.x; As[(e0 + 1) * 64 + r] = v.y;
                As[(e0 + 2) * 64 + r] = v.z; As[(e0 + 3) * 64 + r] = v.w;
            }
        }
        {
            int d = t & 127, eb = (t >> 7) * 32;
#pragma unroll
            for (int rep = 0; rep < 8; ++rep) {
                int e0 = eb + rep * 4;
                float4 v = *(const float4*)&W[(d0 + d) * EDIM + e0];
                Bs[(e0 + 0) * 128 + d] = v.x; Bs[(e0 + 1) * 128 + d] = v.y;
                Bs[(e0 + 2) * 128 + d] = v.z; Bs[(e0 + 3) * 128 + d] = v.w;
            }
        }
        __syncthreads();
        float acc[4][8];
#pragma unroll
        for (int i = 0; i < 4; ++i)
#pragma unroll
            for (int j = 0; j < 8; ++j) acc[i][j] = 0.f;
#pragma unroll 4
        for (int e = 0; e < 64; ++e) {
            float4 a  = *(const float4*)&As[e * 64 + ty * 4];
            float4 b0 = *(const float4*)&Bs[e * 128 + tx * 4];
            float4 b1 = *(const float4*)&Bs[e * 128 + 64 + tx * 4];
            float ar[4] = {a.x, a.y, a.z, a.w};
#pragma unroll
            for (int i = 0; i < 4; ++i) {
                acc[i][0] = fmaf(ar[i], b0.x, acc[i][0]);
                acc[i][1] = fmaf(ar[i], b0.y, acc[i][1]);
                acc[i][2] = fmaf(ar[i], b0.z, acc[i][2]);
                acc[i][3] = fmaf(ar[i], b0.w, acc[i][3]);
                acc[i][4] = fmaf(ar[i], b1.x, acc[i][4]);
                acc[i][5] = fmaf(ar[i], b1.y, acc[i][5]);
                acc[i][6] = fmaf(ar[i], b1.z, acc[i][6]);
                acc[i][7] = fmaf(ar[i], b1.w, acc[i][7]);
            }
        }
        float4 bias0 = *(const float4*)&b[d0 + tx * 4];
        float4 bias1 = *(const float4*)&b[d0 + 64 + tx * 4];
#pragma unroll
        for (int i = 0; i < 4; ++i) {
            int r = r0 + ty * 4 + i;
            float4 o0 = make_float4(acc[i][0] + bias0.x, acc[i][1] + bias0.y,
                                    acc[i][2] + bias0.z, acc[i][3] + bias0.w);
            float4 o1 = make_float4(acc[i][4] + bias1.x, acc[i][5] + bias1.y,
                                    acc[i][6] + bias1.z, acc[i][7] + bias1.w);
            *(float4*)&out[r * DQK + d0 + tx * 4] = o0;
            *(float4*)&out[r * DQK + d0 + 64 + tx * 4] = o1;
        }
        return;
    }

    // ---------------- MFMA coarse top-8 path ----------------
    // block: 64 rows x (TPS x 128 cands). wave w: rows r0+w*16..+15.
    // mfma_f32_16x16x32_bf16: A/B frag = 8 contiguous k at row lane&15, k-half lane>>4;
    // C: col=lane&15, row=(lane>>4)*4+reg  [m89/m120-verified layouts]
    int id = blockIdx.x - QKV_BLOCKS;
    int rb = id % 96, sp = id / 96;
    int r0 = rb * 64;
    int w = t >> 6, lane = t & 63, lq = lane >> 4, lc = lane & 15;

    short* Ah = (short*)smem;            // [64][64] bf16 row-major, 8 KB (read 2x per wave only)
    short* Bh = Ah + 64 * EDIM;          // [128][BSTR=72] bf16 padded, 18 KB, conflict-free b128

    { // stage A (Qm bf16 rows r0..r0+63) once: 512 float4
        const float4* Ag = (const float4*)(Qmh + (size_t)r0 * EDIM);
        float4* AhV = (float4*)Ah;
        AhV[t] = Ag[t];
        AhV[t + 256] = Ag[t + 256];
    }

    // per-thread B staging coords: 4 float4 per tile; v = t + 256*rep; row = v>>3, col8 = v&7
    float4 pf[4];
    { // prefetch tile 0
        int c0 = (sp * TPS) * 128;
#pragma unroll
        for (int rep = 0; rep < 4; ++rep) {
            int v = t + 256 * rep;
            pf[rep] = *(const float4*)&E2h[(size_t)(c0 + (v >> 3)) * EDIM + (v & 7) * 8];
        }
    }

    float t3v[4][3]; int t3i[4][3];
#pragma unroll
    for (int i = 0; i < 4; ++i)
#pragma unroll
        for (int k = 0; k < 3; ++k) { t3v[i][k] = -INFINITY; t3i[i][k] = 0x7fffffff; }

    bf16x8 af0, af1;
    for (int tile = 0; tile < TPS; ++tile) {
        int c0 = (sp * TPS + tile) * 128;
        __syncthreads();    // previous tile's B consumed (tile0: A-store also drains)
        { // write prefetched tile into padded LDS
#pragma unroll
            for (int rep = 0; rep < 4; ++rep) {
                int v = t + 256 * rep;
                *(float4*)&Bh[(v >> 3) * BSTR + (v & 7) * 8] = pf[rep];
            }
        }
        if (tile + 1 < TPS) { // prefetch next tile; lands during this tile's compute
            int c1 = c0 + 128;
#pragma unroll
            for (int rep = 0; rep < 4; ++rep) {
                int v = t + 256 * rep;
                pf[rep] = *(const float4*)&E2h[(size_t)(c1 + (v >> 3)) * EDIM + (v & 7) * 8];
            }
        }
        __syncthreads();
        if (tile == 0) {
            af0 = *(const bf16x8*)&Ah[(w * 16 + lc) * EDIM + lq * 8];
            af1 = *(const bf16x8*)&Ah[(w * 16 + lc) * EDIM + 32 + lq * 8];
        }

#pragma unroll
        for (int ch = 0; ch < 8; ++ch) {
            bf16x8 b0 = *(const bf16x8*)&Bh[(ch * 16 + lc) * BSTR + lq * 8];
            bf16x8 b1 = *(const bf16x8*)&Bh[(ch * 16 + lc) * BSTR + 32 + lq * 8];
            f32x4 acc = {0.f, 0.f, 0.f, 0.f};
            acc = __builtin_amdgcn_mfma_f32_16x16x32_bf16(af0, b0, acc, 0, 0, 0);
            acc = __builtin_amdgcn_mfma_f32_16x16x32_bf16(af1, b1, acc, 0, 0, 0);
            int ci = c0 + ch * 16 + lc;   // cand index (C col = lane&15)
#pragma unroll
            for (int reg = 0; reg < 4; ++reg)
                ins3(acc[reg], ci, t3v[reg], t3i[reg]);
        }
    }

    // merge 16 lanes' top-3 lists per row -> split top-8 (R5-verified ptr-merge, quad-local)
#pragma unroll
    for (int i = 0; i < 4; ++i) {
        int row = r0 + w * 16 + lq * 4 + i;
        int ptr = 0;
        for (int k = 0; k < CK; ++k) {
            float cvv = (ptr == 0) ? t3v[i][0] : (ptr == 1) ? t3v[i][1]
                      : (ptr == 2) ? t3v[i][2] : -INFINITY;
            int   cii = (ptr == 0) ? t3i[i][0] : (ptr == 1) ? t3i[i][1]
                      : (ptr == 2) ? t3i[i][2] : 0x7fffffff;
            float bv = cvv; int bi = cii;
#pragma unroll
            for (int off = 1; off < 16; off <<= 1) {
                float ov = __shfl_xor(bv, off, 64);
                int   oi = __shfl_xor(bi, off, 64);
                if (ov > bv || (ov == bv && oi < bi)) { bv = ov; bi = oi; }
            }
            if (bv == cvv && bi == cii) ptr++;
            if (lc == 0) pidx[(row * SPLITS + sp) * CK + k] = bi;
        }
    }
}

// ================================================================ exact rescore + top-5 + attention
__global__ __launch_bounds__(TPB) void attn_kernel(
        const float* __restrict__ Qm, const float* __restrict__ ego2,
        const float* __restrict__ Qa, const float* __restrict__ Ka, const float* __restrict__ Va,
        const int* __restrict__ pidx, float* __restrict__ out) {
    int wv = threadIdx.x >> 6, lane = threadIdx.x & 63;
    int r = blockIdx.x * 4 + wv;
    // 64 coarse candidates (8 splits x 8); rescore exactly in fp32
    int ci0 = pidx[r * (SPLITS * CK) + lane];
    const float4* qm4 = (const float4*)(Qm + (size_t)r * EDIM);
    const float4* e24 = (const float4*)(ego2 + (size_t)ci0 * EDIM);
    float sv = 0.f;
#pragma unroll
    for (int e = 0; e < 16; ++e) {
        float4 a = qm4[e], b = e24[e];
        sv = fmaf(a.x, b.x, sv); sv = fmaf(a.y, b.y, sv);
        sv = fmaf(a.z, b.z, sv); sv = fmaf(a.w, b.w, sv);
    }

    float prevv = INFINITY; int previ = -1;
    int cI[KTOP];
#pragma unroll
    for (int k = 0; k < KTOP; ++k) {
        bool adm = (sv < prevv) || (sv == prevv && ci0 > previ);
        float bv = adm ? sv : -INFINITY;
        int   bi = adm ? ci0 : 0x7fffffff;
#pragma unroll
        for (int off = 1; off < 64; off <<= 1) {
            float ov = __shfl_xor(bv, off, 64);
            int   oi = __shfl_xor(bi, off, 64);
            if (ov > bv || (ov == bv && oi < bi)) { bv = ov; bi = oi; }
        }
        cI[k] = bi; prevv = bv; previ = bi;
    }

    float4 q = *(const float4*)&Qa[r * DQK + lane * 4];
    float sc[KTOP];
#pragma unroll
    for (int k = 0; k < KTOP; ++k) {
        float4 kk = *(const float4*)&Ka[cI[k] * DQK + lane * 4];
        float p = q.x * kk.x + q.y * kk.y + q.z * kk.z + q.w * kk.w;
#pragma unroll
        for (int off = 32; off; off >>= 1) p += __shfl_xor(p, off, 64);
        sc[k] = p * 0.0625f;   // 1/sqrt(256)
    }
    float m = sc[0];
#pragma unroll
    for (int k = 1; k < KTOP; ++k) m = fmaxf(m, sc[k]);
    float wgt[KTOP], ssum = 0.f;
#pragma unroll
    for (int k = 0; k < KTOP; ++k) { wgt[k] = expf(sc[k] - m); ssum += wgt[k]; }
    float inv = 1.f / ssum;
    float4 o = make_float4(0.f, 0.f, 0.f, 0.f);
#pragma unroll
    for (int k = 0; k < KTOP; ++k) {
        float4 vv = *(const float4*)&Va[cI[k] * DQK + lane * 4];
        float a = wgt[k] * inv;
        o.x = fmaf(a, vv.x, o.x); o.y = fmaf(a, vv.y, o.y);
        o.z = fmaf(a, vv.z, o.z); o.w = fmaf(a, vv.w, o.w);
    }
    *(float4*)&out[r * DQK + lane * 4] = o;
}

// ================================================================ launch
extern "C" void kernel_launch(void* const* d_in, const int* in_sizes, int n_in,
                              void* d_out, int out_size, void* d_ws, size_t ws_size,
                              hipStream_t stream) {
    const float* user  = (const float*)d_in[0];
    const float* item  = (const float*)d_in[1];
    const int*   nrows = (const int*)d_in[2];
    const int*   ncols = (const int*)d_in[3];
    const float* nvals = (const float*)d_in[4];
    const int*   arows = (const int*)d_in[5];
    const int*   acols = (const int*)d_in[6];
    const float* avals = (const float*)d_in[7];
    const float* Wq = (const float*)d_in[8];  const float* bq = (const float*)d_in[9];
    const float* Wk = (const float*)d_in[10]; const float* bk = (const float*)d_in[11];
    const float* Wv = (const float*)d_in[12]; const float* bv = (const float*)d_in[13];
    float* out = (float*)d_out;
    float* ws  = (float*)d_ws;

    const int NE  = NN * EDIM;             // 393216
    const int NQK = NN * DQK;              // 1572864
    float* ego1 = ws;
    float* ego2 = ws + NE;
    float* Qm   = ws + 2 * NE;
    float* Qa   = ws + 3 * NE;
    float* Ka   = Qa + NQK;
    float* Va   = Ka + NQK;
    int*   pidx = (int*)(Va + NQK);                       // NN*SPLITS*CK ints
    unsigned short* Qmh = (unsigned short*)(pidx + NN * SPLITS * CK);
    unsigned short* E2h = Qmh + NE;

    // ELL scratch aliased over Qa..Va (dead until qkv_topk)
    int* ell    = (int*)Qa;
    int* cnt_n  = ell;                     // 6144
    int* cnt_a  = ell + 6144;              // 6144
    int2* cv_n  = (int2*)(ell + 12288);    // 6144*96 int2
    int2* cv_a  = cv_n + NN * ELLW;

    hipMemsetAsync(cnt_n, 0, 12288 * sizeof(int), stream);
    build_kernel<<<(2 * NNZ + TPB - 1) / TPB, TPB, 0, stream>>>(nrows, ncols, nvals,
                                                                arows, acols, avals,
                                                                cnt_n, cnt_a, cv_n, cv_a);
    spmm_ell_emb_kernel<<<NN / 4, TPB, 0, stream>>>(cnt_n, cv_n, user, item, ego1);
    spmm_ell_kernel<<<NN / 4, TPB, 0, stream>>>(cnt_n, cv_n, ego1, ego2);
    qm_mean_kernel<<<NN / 4, TPB, 0, stream>>>(cnt_a, cv_a, ego2, ego1, user, item,
                                               Qm, out, Qmh, E2h);
    qkv_topk_kernel<<<QKV_BLOCKS + TOPK_BLOCKS, TPB, 0, stream>>>(
        ego2, Wq, bq, Wk, bk, Wv, bv, Qa, Ka, Va, Qmh, E2h, pidx);
    attn_kernel<<<NN / 4, TPB, 0, stream>>>(Qm, ego2, Qa, Ka, Va, pidx, out + NE);
}